// Round 2
// baseline (1597.225 us; speedup 1.0000x reference)
//
#include <hip/hip_runtime.h>
#include <math.h>

constexpr int Bc = 4, Hc = 48, Wc = 48, Cc = 256;
constexpr int NQc = 8, HWc = 2304, Nc = 2312, NHc = 8, Dc = 32, FFNc = 1024;
constexpr int MRc = Bc * Nc; // 9248

// ---------------- pos dwconv 3x3 + residual -> xq spatial rows ----------------
__global__ void pos_conv_kernel(const float* __restrict__ x, const float* __restrict__ w,
                                const float* __restrict__ bias, float* __restrict__ xq)
{
    int idx = blockIdx.x * 256 + threadIdx.x;
    if (idx >= Bc * Hc * Wc * Cc) return;
    int c  = idx & (Cc - 1);
    int sp = idx >> 8;
    int ww = sp % Wc;
    int t2 = sp / Wc;
    int hh = t2 % Hc;
    int b  = t2 / Hc;
    float acc = bias[c];
    float center = x[idx];
#pragma unroll
    for (int kh = 0; kh < 3; ++kh) {
        int yy = hh + kh - 1;
        if (yy < 0 || yy >= Hc) continue;
#pragma unroll
        for (int kw = 0; kw < 3; ++kw) {
            int xx = ww + kw - 1;
            if (xx < 0 || xx >= Wc) continue;
            acc += x[((b * Hc + yy) * Wc + xx) * Cc + c] * w[(kh * 3 + kw) * Cc + c];
        }
    }
    xq[((size_t)b * Nc + NQc + hh * Wc + ww) * Cc + c] = center + acc;
}

__global__ void fill_queries_kernel(const float* __restrict__ q, float* __restrict__ xq)
{
    int idx = blockIdx.x * 256 + threadIdx.x;
    if (idx >= Bc * NQc * Cc) return;
    int c = idx & (Cc - 1);
    int n = (idx >> 8) & (NQc - 1);
    int b = idx >> 11;
    xq[((size_t)b * Nc + n) * Cc + c] = q[idx];
}

// ---------------- region softmax p = softmax(xf @ queries^T / tau) ----------------
__global__ void region_p_kernel(const float* __restrict__ xq, const float* __restrict__ queries,
                                const int* __restrict__ epoch, float* __restrict__ p)
{
    int gid  = blockIdx.x * blockDim.x + threadIdx.x;
    int wid  = gid >> 6;
    int lane = gid & 63;
    if (wid >= Bc * HWc) return;
    int b = wid / HWc, n = wid - b * HWc;
    const float* xr = xq + ((size_t)b * Nc + NQc + n) * Cc;
    float acc[8] = {0, 0, 0, 0, 0, 0, 0, 0};
    for (int c = lane; c < Cc; c += 64) {
        float xv = xr[c];
#pragma unroll
        for (int qi = 0; qi < 8; ++qi)
            acc[qi] += xv * queries[(b * NQc + qi) * Cc + c];
    }
#pragma unroll
    for (int qi = 0; qi < 8; ++qi) {
        float v = acc[qi];
        for (int off = 32; off; off >>= 1) v += __shfl_xor(v, off);
        acc[qi] = v;
    }
    float tau = 2.0f * powf(0.05f, (float)(*epoch) / 200.0f);
    float it  = 1.0f / tau;
    float mx = -1e30f;
#pragma unroll
    for (int qi = 0; qi < 8; ++qi) mx = fmaxf(mx, acc[qi] * it);
    float s = 0.f, e[8];
#pragma unroll
    for (int qi = 0; qi < 8; ++qi) { e[qi] = expf(acc[qi] * it - mx); s += e[qi]; }
    if (lane < 8) p[((size_t)b * HWc + n) * 8 + lane] = e[lane] / s;
}

// ---------------- LayerNorm (wave per row of 256) ----------------
__global__ void ln_kernel(const float* __restrict__ in, const float* __restrict__ g,
                          const float* __restrict__ bb, float* __restrict__ out, int rows)
{
    int gid  = blockIdx.x * blockDim.x + threadIdx.x;
    int wid  = gid >> 6;
    int lane = gid & 63;
    if (wid >= rows) return;
    const float* r = in + (size_t)wid * Cc;
    int c = lane * 4;
    float4 v = *(const float4*)(r + c);
    float s = v.x + v.y + v.z + v.w;
    for (int off = 32; off; off >>= 1) s += __shfl_xor(s, off);
    float mean = s * (1.0f / 256.0f);
    float dx = v.x - mean, dy = v.y - mean, dz = v.z - mean, dw = v.w - mean;
    float ss = dx * dx + dy * dy + dz * dz + dw * dw;
    for (int off = 32; off; off >>= 1) ss += __shfl_xor(ss, off);
    float inv = rsqrtf(ss * (1.0f / 256.0f) + 1e-6f);
    float4 o;
    o.x = dx * inv * g[c + 0] + bb[c + 0];
    o.y = dy * inv * g[c + 1] + bb[c + 1];
    o.z = dz * inv * g[c + 2] + bb[c + 2];
    o.w = dw * inv * g[c + 3] + bb[c + 3];
    *(float4*)(out + (size_t)wid * Cc + c) = o;
}

// ---------------- GEMM: out[m,n] = act((A[m,:] . W[n,:] + bias[n]) * scale) + resid ----------------
template <int ACT>
__global__ __launch_bounds__(256) void gemm_kernel(const float* __restrict__ A, const float* __restrict__ Wt,
                                                   const float* __restrict__ bias, const float* resid,
                                                   float* Cout, int M, int N, int K, float scale)
{
    const int BM = 64, BN = 64, BK = 16;
    __shared__ float As[BK][BM + 4];
    __shared__ float Bs[BK][BN + 4];
    int t  = threadIdx.x;
    int tx = t & 15, ty = t >> 4;
    int m0 = blockIdx.y * BM, n0 = blockIdx.x * BN;
    float acc[4][4] = {};
    int lr  = t >> 2;          // 0..63 tile row
    int seg = (t & 3) * 4;     // k segment
    for (int k0 = 0; k0 < K; k0 += BK) {
        float4 av = make_float4(0.f, 0.f, 0.f, 0.f);
        if (m0 + lr < M) av = *(const float4*)(A + (size_t)(m0 + lr) * K + k0 + seg);
        float4 wv = *(const float4*)(Wt + (size_t)(n0 + lr) * K + k0 + seg);
        __syncthreads();
        As[seg + 0][lr] = av.x;
        As[seg + 1][lr] = av.y;
        As[seg + 2][lr] = av.z;
        As[seg + 3][lr] = av.w;
        Bs[seg + 0][lr] = wv.x;
        Bs[seg + 1][lr] = wv.y;
        Bs[seg + 2][lr] = wv.z;
        Bs[seg + 3][lr] = wv.w;
        __syncthreads();
#pragma unroll
        for (int kk = 0; kk < BK; ++kk) {
            float4 a4 = *(const float4*)&As[kk][ty * 4];
            float4 b4 = *(const float4*)&Bs[kk][tx * 4];
            float a[4] = {a4.x, a4.y, a4.z, a4.w};
            float bvv[4] = {b4.x, b4.y, b4.z, b4.w};
#pragma unroll
            for (int i = 0; i < 4; ++i)
#pragma unroll
                for (int j = 0; j < 4; ++j) acc[i][j] += a[i] * bvv[j];
        }
    }
#pragma unroll
    for (int i = 0; i < 4; ++i) {
        int m = m0 + ty * 4 + i;
        if (m >= M) continue;
#pragma unroll
        for (int j = 0; j < 4; ++j) {
            int n = n0 + tx * 4 + j;
            float v = (acc[i][j] + bias[n]) * scale;
            if (ACT == 1) v = 0.5f * v * (1.0f + erff(v * 0.70710678118654752f));
            if (resid) v += resid[(size_t)m * N + n];
            Cout[(size_t)m * N + n] = v;
        }
    }
}

// ---------------- lepe dwconv 5x5 on v spatial rows, added into attention output ----------------
__global__ void lepe_conv_add_kernel(const float* __restrict__ v, const float* __restrict__ w,
                                     const float* __restrict__ bias, float* __restrict__ o)
{
    int idx = blockIdx.x * 256 + threadIdx.x;
    if (idx >= Bc * HWc * Cc) return;
    int c  = idx & (Cc - 1);
    int sp = idx >> 8;
    int ww = sp % Wc;
    int t2 = sp / Wc;
    int hh = t2 % Hc;
    int b  = t2 / Hc;
    float acc = bias[c];
#pragma unroll
    for (int kh = 0; kh < 5; ++kh) {
        int yy = hh + kh - 2;
        if (yy < 0 || yy >= Hc) continue;
#pragma unroll
        for (int kw = 0; kw < 5; ++kw) {
            int xx = ww + kw - 2;
            if (xx < 0 || xx >= Wc) continue;
            acc += v[((size_t)b * Nc + NQc + yy * Wc + xx) * Cc + c] * w[(kh * 5 + kw) * Cc + c];
        }
    }
    o[((size_t)b * Nc + NQc + hh * Wc + ww) * Cc + c] += acc;
}

// ---------------- flash-style masked attention (vh == scaled k) ----------------
__global__ __launch_bounds__(256) void attn_kernel(const float* __restrict__ q, const float* __restrict__ k,
                                                   const float* __restrict__ p, float* __restrict__ o)
{
    constexpr int MT = 64;
    __shared__ float kls[MT][36];
    __shared__ float pls[MT][8];
    __shared__ float Pls[32][68];
    int b  = blockIdx.z, h = blockIdx.y;
    int n0 = blockIdx.x * 32;
    int t  = threadIdx.x;
    int r   = t >> 3;   // row in block (0..31)
    int sub = t & 7;    // lane within row group
    int n = n0 + r;
    bool valid = n < Nc;
    int nc = valid ? n : Nc - 1;
    const float* qrow = q + ((size_t)b * Nc + nc) * Cc + h * Dc;
    float4 qv[8];
#pragma unroll
    for (int i = 0; i < 8; ++i) qv[i] = *(const float4*)(qrow + i * 4);
    float pn[8];
    bool n_sp = valid && (n >= NQc);
    if (n_sp) {
        const float* pr = p + ((size_t)b * HWc + (n - NQc)) * 8;
#pragma unroll
        for (int i = 0; i < 8; ++i) pn[i] = pr[i];
    } else {
#pragma unroll
        for (int i = 0; i < 8; ++i) pn[i] = 0.f;
    }
    float m_run = 0.f, l_run = 0.f;   // m>=max is valid for softmax; avoids -inf sentinels
    float acc0 = 0.f, acc1 = 0.f, acc2 = 0.f, acc3 = 0.f;

    for (int m0 = 0; m0 < Nc; m0 += MT) {
        // stage k tile (64 x 32 f32)
        int mm  = t >> 2;
        int sg  = (t & 3) * 8;
        int gm  = m0 + mm;
        const float* krow = k + ((size_t)b * Nc + (gm < Nc ? gm : 0)) * Cc + h * Dc + sg;
        float4 a0 = make_float4(0.f, 0.f, 0.f, 0.f), a1 = a0;
        if (gm < Nc) { a0 = *(const float4*)krow; a1 = *(const float4*)(krow + 4); }
        __syncthreads();  // previous tile fully consumed
        *(float4*)&kls[mm][sg]     = a0;
        *(float4*)&kls[mm][sg + 4] = a1;
        if (t < MT) {
            int pm = m0 + t;
            if (pm >= NQc && pm < Nc) {
                const float* pr = p + ((size_t)b * HWc + (pm - NQc)) * 8;
                *(float4*)&pls[t][0] = *(const float4*)pr;
                *(float4*)&pls[t][4] = *(const float4*)(pr + 4);
            } else {
                *(float4*)&pls[t][0] = make_float4(0.f, 0.f, 0.f, 0.f);
                *(float4*)&pls[t][4] = make_float4(0.f, 0.f, 0.f, 0.f);
            }
        }
        __syncthreads();

        float sc[8];
        bool  ok[8];
        float tmax = -1e30f;
#pragma unroll
        for (int j = 0; j < 8; ++j) {
            int mm2 = sub + j * 8;
            int gm2 = m0 + mm2;
            float d = 0.f;
#pragma unroll
            for (int i = 0; i < 8; ++i) {
                float4 k4 = *(const float4*)&kls[mm2][i * 4];
                d += qv[i].x * k4.x + qv[i].y * k4.y + qv[i].z * k4.z + qv[i].w * k4.w;
            }
            float maskv = 1.f;
            if (n_sp && gm2 >= NQc) {
                float4 p0 = *(const float4*)&pls[mm2][0];
                float4 p1 = *(const float4*)&pls[mm2][4];
                maskv = pn[0] * p0.x + pn[1] * p0.y + pn[2] * p0.z + pn[3] * p0.w +
                        pn[4] * p1.x + pn[5] * p1.y + pn[6] * p1.z + pn[7] * p1.w;
            }
            ok[j] = (gm2 < Nc);
            sc[j] = d * maskv;
            if (ok[j]) tmax = fmaxf(tmax, sc[j]);
        }
#pragma unroll
        for (int off = 1; off < 8; off <<= 1) tmax = fmaxf(tmax, __shfl_xor(tmax, off));
        float m_new   = fmaxf(m_run, tmax);
        float rescale = __expf(m_run - m_new);
        float lsum = 0.f;
#pragma unroll
        for (int j = 0; j < 8; ++j) {
            float e = ok[j] ? __expf(sc[j] - m_new) : 0.f;
            lsum += e;
            Pls[r][sub + j * 8] = e;
        }
#pragma unroll
        for (int off = 1; off < 8; off <<= 1) lsum += __shfl_xor(lsum, off);
        l_run = l_run * rescale + lsum;
        m_run = m_new;
        acc0 *= rescale; acc1 *= rescale; acc2 *= rescale; acc3 *= rescale;
        __syncthreads();
        // PV: lane owns d = sub*4 .. +3
#pragma unroll
        for (int m4 = 0; m4 < MT; m4 += 4) {
            float4 pm4 = *(const float4*)&Pls[r][m4];
            float4 k0v = *(const float4*)&kls[m4 + 0][sub * 4];
            float4 k1v = *(const float4*)&kls[m4 + 1][sub * 4];
            float4 k2v = *(const float4*)&kls[m4 + 2][sub * 4];
            float4 k3v = *(const float4*)&kls[m4 + 3][sub * 4];
            acc0 += pm4.x * k0v.x + pm4.y * k1v.x + pm4.z * k2v.x + pm4.w * k3v.x;
            acc1 += pm4.x * k0v.y + pm4.y * k1v.y + pm4.z * k2v.y + pm4.w * k3v.y;
            acc2 += pm4.x * k0v.z + pm4.y * k1v.z + pm4.z * k2v.z + pm4.w * k3v.z;
            acc3 += pm4.x * k0v.w + pm4.y * k1v.w + pm4.z * k2v.w + pm4.w * k3v.w;
        }
    }
    if (valid) {
        float inv = 1.f / l_run;
        float4 res = make_float4(acc0 * inv, acc1 * inv, acc2 * inv, acc3 * inv);
        *(float4*)(o + ((size_t)b * Nc + n) * Cc + h * Dc + sub * 4) = res;
    }
}

__global__ void write_out_kernel(const float* __restrict__ xq, float* __restrict__ out)
{
    int idx = blockIdx.x * 256 + threadIdx.x;
    const int SP = Bc * HWc * Cc;
    if (idx < SP) {
        int c  = idx & (Cc - 1);
        int sp = idx >> 8;
        int hw = sp % HWc;
        int b  = sp / HWc;
        out[idx] = xq[((size_t)b * Nc + NQc + hw) * Cc + c];
    } else if (idx < SP + Bc * NQc * Cc) {
        int j = idx - SP;
        int c = j & (Cc - 1);
        int t2 = j >> 8;
        int n = t2 & (NQc - 1);
        int b = t2 >> 3;
        out[idx] = xq[((size_t)b * Nc + n) * Cc + c];
    }
}

extern "C" void kernel_launch(void* const* d_in, const int* in_sizes, int n_in,
                              void* d_out, int out_size, void* d_ws, size_t ws_size,
                              hipStream_t stream)
{
    const float* x       = (const float*)d_in[0];
    const float* queries = (const float*)d_in[1];
    const int*   epoch   = (const int*)d_in[2];
    const float* pos_w   = (const float*)d_in[3];
    const float* pos_b   = (const float*)d_in[4];
    const float* ln1_g   = (const float*)d_in[5];
    const float* ln1_b   = (const float*)d_in[6];
    const float* q_w     = (const float*)d_in[7];
    const float* q_b     = (const float*)d_in[8];
    const float* k_w     = (const float*)d_in[9];
    const float* k_b     = (const float*)d_in[10];
    const float* v_w     = (const float*)d_in[11];
    const float* v_b     = (const float*)d_in[12];
    const float* lepe_w  = (const float*)d_in[13];
    const float* lepe_b  = (const float*)d_in[14];
    const float* out_w   = (const float*)d_in[15];
    const float* out_b   = (const float*)d_in[16];
    const float* ln2_g   = (const float*)d_in[17];
    const float* ln2_b   = (const float*)d_in[18];
    const float* fc1_w   = (const float*)d_in[19];
    const float* fc1_b   = (const float*)d_in[20];
    const float* fc2_w   = (const float*)d_in[21];
    const float* fc2_b   = (const float*)d_in[22];

    float* ws   = (float*)d_ws;
    float* xq   = ws;                  // 2367488
    float* y    = ws + 2367488;        // 2367488
    float* qb   = ws + 4734976;        // 2367488
    float* kb   = ws + 7102464;        // 2367488
    float* vb   = ws + 9469952;        // 2367488
    float* ob   = ws + 11837440;       // 2367488
    float* pbuf = ws + 14204928;       // 73728
    float* ffn  = qb;                  // fc1 act reuses q/k/v/o region (9469952 floats)

    const float kscale = 0.17677669529663687f; // (256/8)^-0.5

    pos_conv_kernel<<<9216, 256, 0, stream>>>(x, pos_w, pos_b, xq);
    fill_queries_kernel<<<32, 256, 0, stream>>>(queries, xq);
    region_p_kernel<<<2304, 256, 0, stream>>>(xq, queries, epoch, pbuf);
    ln_kernel<<<2312, 256, 0, stream>>>(xq, ln1_g, ln1_b, y, MRc);

    dim3 g256(4, 145);
    gemm_kernel<0><<<g256, 256, 0, stream>>>(y, q_w, q_b, nullptr, qb, MRc, 256, 256, 1.0f);
    gemm_kernel<0><<<g256, 256, 0, stream>>>(y, k_w, k_b, nullptr, kb, MRc, 256, 256, kscale);
    gemm_kernel<0><<<g256, 256, 0, stream>>>(y, v_w, v_b, nullptr, vb, MRc, 256, 256, 1.0f);

    attn_kernel<<<dim3(73, 8, 4), 256, 0, stream>>>(qb, kb, pbuf, ob);
    lepe_conv_add_kernel<<<9216, 256, 0, stream>>>(vb, lepe_w, lepe_b, ob);

    gemm_kernel<0><<<g256, 256, 0, stream>>>(ob, out_w, out_b, xq, xq, MRc, 256, 256, 1.0f);

    ln_kernel<<<2312, 256, 0, stream>>>(xq, ln2_g, ln2_b, y, MRc);
    gemm_kernel<1><<<dim3(16, 145), 256, 0, stream>>>(y, fc1_w, fc1_b, nullptr, ffn, MRc, 1024, 256, 1.0f);
    gemm_kernel<0><<<g256, 256, 0, stream>>>(ffn, fc2_w, fc2_b, xq, xq, MRc, 256, 1024, 1.0f);

    write_out_kernel<<<9248, 256, 0, stream>>>(xq, (float*)d_out);
}

// Round 3
// 569.647 us; speedup vs baseline: 2.8039x; 2.8039x over previous
//
#include <hip/hip_runtime.h>
#include <math.h>

constexpr int Bc = 4, Hc = 48, Wc = 48, Cc = 256;
constexpr int NQc = 8, HWc = 2304, Nc = 2312, NHc = 8, Dc = 32, FFNc = 1024;
constexpr int MRc = Bc * Nc; // 9248

typedef __attribute__((ext_vector_type(8))) short s8v;
typedef __attribute__((ext_vector_type(4))) float f32x4;

__device__ __forceinline__ unsigned short f2bf(float f) {
    unsigned u = __float_as_uint(f);
    u += 0x7fff + ((u >> 16) & 1);
    return (unsigned short)(u >> 16);
}
__device__ __forceinline__ s8v pack8(const float* v) {
    union { unsigned short u[8]; s8v s; } r;
#pragma unroll
    for (int i = 0; i < 8; ++i) r.u[i] = f2bf(v[i]);
    return r.s;
}

// ---------------- pos dwconv 3x3 + residual -> xq spatial rows ----------------
__global__ void pos_conv_kernel(const float* __restrict__ x, const float* __restrict__ w,
                                const float* __restrict__ bias, float* __restrict__ xq)
{
    int idx = blockIdx.x * 256 + threadIdx.x;
    if (idx >= Bc * Hc * Wc * Cc) return;
    int c  = idx & (Cc - 1);
    int sp = idx >> 8;
    int ww = sp % Wc;
    int t2 = sp / Wc;
    int hh = t2 % Hc;
    int b  = t2 / Hc;
    float acc = bias[c];
    float center = x[idx];
#pragma unroll
    for (int kh = 0; kh < 3; ++kh) {
        int yy = hh + kh - 1;
        if (yy < 0 || yy >= Hc) continue;
#pragma unroll
        for (int kw = 0; kw < 3; ++kw) {
            int xx = ww + kw - 1;
            if (xx < 0 || xx >= Wc) continue;
            acc += x[((b * Hc + yy) * Wc + xx) * Cc + c] * w[(kh * 3 + kw) * Cc + c];
        }
    }
    xq[((size_t)b * Nc + NQc + hh * Wc + ww) * Cc + c] = center + acc;
}

__global__ void fill_queries_kernel(const float* __restrict__ q, float* __restrict__ xq)
{
    int idx = blockIdx.x * 256 + threadIdx.x;
    if (idx >= Bc * NQc * Cc) return;
    int c = idx & (Cc - 1);
    int n = (idx >> 8) & (NQc - 1);
    int b = idx >> 11;
    xq[((size_t)b * Nc + n) * Cc + c] = q[idx];
}

// ---------------- region softmax p = softmax(xf @ queries^T / tau) ----------------
__global__ void region_p_kernel(const float* __restrict__ xq, const float* __restrict__ queries,
                                const int* __restrict__ epoch, float* __restrict__ p)
{
    int gid  = blockIdx.x * blockDim.x + threadIdx.x;
    int wid  = gid >> 6;
    int lane = gid & 63;
    if (wid >= Bc * HWc) return;
    int b = wid / HWc, n = wid - b * HWc;
    const float* xr = xq + ((size_t)b * Nc + NQc + n) * Cc;
    float acc[8] = {0, 0, 0, 0, 0, 0, 0, 0};
    for (int c = lane; c < Cc; c += 64) {
        float xv = xr[c];
#pragma unroll
        for (int qi = 0; qi < 8; ++qi)
            acc[qi] += xv * queries[(b * NQc + qi) * Cc + c];
    }
#pragma unroll
    for (int qi = 0; qi < 8; ++qi) {
        float v = acc[qi];
        for (int off = 32; off; off >>= 1) v += __shfl_xor(v, off);
        acc[qi] = v;
    }
    float tau = 2.0f * powf(0.05f, (float)(*epoch) / 200.0f);
    float it  = 1.0f / tau;
    float mx = -1e30f;
#pragma unroll
    for (int qi = 0; qi < 8; ++qi) mx = fmaxf(mx, acc[qi] * it);
    float s = 0.f, e[8];
#pragma unroll
    for (int qi = 0; qi < 8; ++qi) { e[qi] = expf(acc[qi] * it - mx); s += e[qi]; }
    if (lane < 8) p[((size_t)b * HWc + n) * 8 + lane] = e[lane] / s;
}

// ---------------- LayerNorm (wave per row of 256) ----------------
__global__ void ln_kernel(const float* __restrict__ in, const float* __restrict__ g,
                          const float* __restrict__ bb, float* __restrict__ out, int rows)
{
    int gid  = blockIdx.x * blockDim.x + threadIdx.x;
    int wid  = gid >> 6;
    int lane = gid & 63;
    if (wid >= rows) return;
    const float* r = in + (size_t)wid * Cc;
    int c = lane * 4;
    float4 v = *(const float4*)(r + c);
    float s = v.x + v.y + v.z + v.w;
    for (int off = 32; off; off >>= 1) s += __shfl_xor(s, off);
    float mean = s * (1.0f / 256.0f);
    float dx = v.x - mean, dy = v.y - mean, dz = v.z - mean, dw = v.w - mean;
    float ss = dx * dx + dy * dy + dz * dz + dw * dw;
    for (int off = 32; off; off >>= 1) ss += __shfl_xor(ss, off);
    float inv = rsqrtf(ss * (1.0f / 256.0f) + 1e-6f);
    float4 o;
    o.x = dx * inv * g[c + 0] + bb[c + 0];
    o.y = dy * inv * g[c + 1] + bb[c + 1];
    o.z = dz * inv * g[c + 2] + bb[c + 2];
    o.w = dw * inv * g[c + 3] + bb[c + 3];
    *(float4*)(out + (size_t)wid * Cc + c) = o;
}

// ---------------- GEMM: out[m,n] = act((A[m,:] . W[n,:] + bias[n]) * scale) + resid ----------------
template <int ACT>
__global__ __launch_bounds__(256) void gemm_kernel(const float* __restrict__ A, const float* __restrict__ Wt,
                                                   const float* __restrict__ bias, const float* resid,
                                                   float* Cout, int M, int N, int K, float scale)
{
    const int BM = 64, BN = 64, BK = 16;
    __shared__ float As[BK][BM + 4];
    __shared__ float Bs[BK][BN + 4];
    int t  = threadIdx.x;
    int tx = t & 15, ty = t >> 4;
    int m0 = blockIdx.y * BM, n0 = blockIdx.x * BN;
    float acc[4][4] = {};
    int lr  = t >> 2;          // 0..63 tile row
    int seg = (t & 3) * 4;     // k segment
    for (int k0 = 0; k0 < K; k0 += BK) {
        float4 av = make_float4(0.f, 0.f, 0.f, 0.f);
        if (m0 + lr < M) av = *(const float4*)(A + (size_t)(m0 + lr) * K + k0 + seg);
        float4 wv = *(const float4*)(Wt + (size_t)(n0 + lr) * K + k0 + seg);
        __syncthreads();
        As[seg + 0][lr] = av.x;
        As[seg + 1][lr] = av.y;
        As[seg + 2][lr] = av.z;
        As[seg + 3][lr] = av.w;
        Bs[seg + 0][lr] = wv.x;
        Bs[seg + 1][lr] = wv.y;
        Bs[seg + 2][lr] = wv.z;
        Bs[seg + 3][lr] = wv.w;
        __syncthreads();
#pragma unroll
        for (int kk = 0; kk < BK; ++kk) {
            float4 a4 = *(const float4*)&As[kk][ty * 4];
            float4 b4 = *(const float4*)&Bs[kk][tx * 4];
            float a[4] = {a4.x, a4.y, a4.z, a4.w};
            float bvv[4] = {b4.x, b4.y, b4.z, b4.w};
#pragma unroll
            for (int i = 0; i < 4; ++i)
#pragma unroll
                for (int j = 0; j < 4; ++j) acc[i][j] += a[i] * bvv[j];
        }
    }
#pragma unroll
    for (int i = 0; i < 4; ++i) {
        int m = m0 + ty * 4 + i;
        if (m >= M) continue;
#pragma unroll
        for (int j = 0; j < 4; ++j) {
            int n = n0 + tx * 4 + j;
            float v = (acc[i][j] + bias[n]) * scale;
            if (ACT == 1) v = 0.5f * v * (1.0f + erff(v * 0.70710678118654752f));
            if (resid) v += resid[(size_t)m * N + n];
            Cout[(size_t)m * N + n] = v;
        }
    }
}

// ---------------- lepe dwconv 5x5 on v spatial rows, added into attention output ----------------
__global__ void lepe_conv_add_kernel(const float* __restrict__ v, const float* __restrict__ w,
                                     const float* __restrict__ bias, float* __restrict__ o)
{
    int idx = blockIdx.x * 256 + threadIdx.x;
    if (idx >= Bc * HWc * Cc) return;
    int c  = idx & (Cc - 1);
    int sp = idx >> 8;
    int ww = sp % Wc;
    int t2 = sp / Wc;
    int hh = t2 % Hc;
    int b  = t2 / Hc;
    float acc = bias[c];
#pragma unroll
    for (int kh = 0; kh < 5; ++kh) {
        int yy = hh + kh - 2;
        if (yy < 0 || yy >= Hc) continue;
#pragma unroll
        for (int kw = 0; kw < 5; ++kw) {
            int xx = ww + kw - 2;
            if (xx < 0 || xx >= Wc) continue;
            acc += v[((size_t)b * Nc + NQc + yy * Wc + xx) * Cc + c] * w[(kh * 5 + kw) * Cc + c];
        }
    }
    o[((size_t)b * Nc + NQc + hh * Wc + ww) * Cc + c] += acc;
}

// ---------------- MFMA flash attention (vh == scaled k), rank-8 mask via MFMA ----------------
// block: 256 thr = 4 waves; wave w owns 16 q-rows; KV tile = 64.
__global__ __launch_bounds__(256, 2) void attn_mfma_kernel(const float* __restrict__ q,
                                                           const float* __restrict__ k,
                                                           const float* __restrict__ p,
                                                           float* __restrict__ o)
{
    constexpr int KT = 64;
    __shared__ unsigned short Kls[KT * 40];   // [kv][d] bf16, stride 40 (2-way bank)
    __shared__ unsigned short Ktls[32 * 88];  // [d][kv] bf16, stride 88 (2-way bank)
    __shared__ unsigned short Pkls[KT * 8];   // [kv][8] p bf16
    __shared__ float Pls[4][16 * 76];         // per-wave P tile, stride 76 (2-way bank)

    int b = blockIdx.z, h = blockIdx.y;
    int t = threadIdx.x;
    int w = t >> 6;
    int l = t & 63;
    int lg = l >> 4;   // lane group 0..3
    int lr = l & 15;
    int q0 = blockIdx.x * 64 + w * 16;

    // Q fragment: A[row=lr][k=lg*8+j]
    int qrow = q0 + lr;
    int qrc  = qrow < Nc ? qrow : Nc - 1;
    const float* qp = q + ((size_t)b * Nc + qrc) * Cc + h * Dc + lg * 8;
    float qtmp[8];
    *(float4*)&qtmp[0] = *(const float4*)qp;
    *(float4*)&qtmp[4] = *(const float4*)(qp + 4);
    s8v qA = pack8(qtmp);

    // pq fragment (K padded 8->32: only lane-group 0 nonzero)
    s8v pqA = {0, 0, 0, 0, 0, 0, 0, 0};
    if (lg == 0 && qrow >= NQc && qrow < Nc) {
        const float* pp = p + ((size_t)b * HWc + (qrow - NQc)) * 8;
        float pt[8];
        *(float4*)&pt[0] = *(const float4*)pp;
        *(float4*)&pt[4] = *(const float4*)(pp + 4);
        pqA = pack8(pt);
    }

    f32x4 accO[2] = {{0.f, 0.f, 0.f, 0.f}, {0.f, 0.f, 0.f, 0.f}};
    float mrun[4] = {-1e30f, -1e30f, -1e30f, -1e30f};
    float lrun[4] = {0.f, 0.f, 0.f, 0.f};

    int srow = t >> 2;        // staging row 0..63
    int sseg = (t & 3) * 8;   // d segment
    int prow = t >> 1, pseg = (t & 1) * 4;

    for (int m0 = 0; m0 < Nc; m0 += KT) {
        // ---- fetch K tile + p tile (to regs) ----
        float kt[8];
        int kvg = m0 + srow;
        if (kvg < Nc) {
            const float* kp = k + ((size_t)b * Nc + kvg) * Cc + h * Dc + sseg;
            *(float4*)&kt[0] = *(const float4*)kp;
            *(float4*)&kt[4] = *(const float4*)(kp + 4);
        } else {
#pragma unroll
            for (int i = 0; i < 8; ++i) kt[i] = 0.f;
        }
        float pt4[4] = {0.f, 0.f, 0.f, 0.f};
        if (t < 128) {
            int pg = m0 + prow;
            if (pg >= NQc && pg < Nc)
                *(float4*)pt4 = *(const float4*)(p + ((size_t)b * HWc + (pg - NQc)) * 8 + pseg);
        }
        __syncthreads();  // previous tile fully consumed
        s8v kb8 = pack8(kt);
        *(s8v*)&Kls[srow * 40 + sseg] = kb8;
        {
            union { s8v s; unsigned short u[8]; } kk; kk.s = kb8;
#pragma unroll
            for (int i = 0; i < 8; ++i) Ktls[(sseg + i) * 88 + srow] = kk.u[i];
        }
        if (t < 128) {
            ushort4 pu;
            pu.x = f2bf(pt4[0]); pu.y = f2bf(pt4[1]); pu.z = f2bf(pt4[2]); pu.w = f2bf(pt4[3]);
            *(ushort4*)&Pkls[prow * 8 + pseg] = pu;
        }
        __syncthreads();

        // ---- S tiles: QK^T * mask, online softmax ----
        float sc[4][4];
        float tmax[4] = {-1e30f, -1e30f, -1e30f, -1e30f};
#pragma unroll
        for (int cb = 0; cb < 4; ++cb) {
            s8v kB = *(s8v*)&Kls[(cb * 16 + lr) * 40 + lg * 8];
            f32x4 S = __builtin_amdgcn_mfma_f32_16x16x32_bf16(qA, kB, (f32x4){0.f, 0.f, 0.f, 0.f}, 0, 0, 0);
            s8v pB = {0, 0, 0, 0, 0, 0, 0, 0};
            if (lg == 0) pB = *(s8v*)&Pkls[(cb * 16 + lr) * 8];
            f32x4 Mv = __builtin_amdgcn_mfma_f32_16x16x32_bf16(pqA, pB, (f32x4){0.f, 0.f, 0.f, 0.f}, 0, 0, 0);
            int colg = m0 + cb * 16 + lr;
#pragma unroll
            for (int j = 0; j < 4; ++j) {
                int rowg = q0 + lg * 4 + j;
                float mv = (rowg < NQc || colg < NQc) ? 1.f : Mv[j];
                float s = S[j] * mv;
                if (colg >= Nc) s = -1e30f;
                sc[cb][j] = s;
                tmax[j] = fmaxf(tmax[j], s);
            }
        }
#pragma unroll
        for (int j = 0; j < 4; ++j) {
            float v = tmax[j];
            v = fmaxf(v, __shfl_xor(v, 1));
            v = fmaxf(v, __shfl_xor(v, 2));
            v = fmaxf(v, __shfl_xor(v, 4));
            v = fmaxf(v, __shfl_xor(v, 8));
            float mnew = fmaxf(mrun[j], v);
            float scl  = __expf(mrun[j] - mnew);
            mrun[j] = mnew;
            accO[0][j] *= scl;
            accO[1][j] *= scl;
            lrun[j] *= scl;
        }
        float lsum[4] = {0.f, 0.f, 0.f, 0.f};
#pragma unroll
        for (int cb = 0; cb < 4; ++cb)
#pragma unroll
            for (int j = 0; j < 4; ++j) {
                float ev = __expf(sc[cb][j] - mrun[j]);
                sc[cb][j] = ev;
                lsum[j] += ev;
            }
#pragma unroll
        for (int j = 0; j < 4; ++j) {
            float v = lsum[j];
            v += __shfl_xor(v, 1);
            v += __shfl_xor(v, 2);
            v += __shfl_xor(v, 4);
            v += __shfl_xor(v, 8);
            lrun[j] += v;
        }
        // ---- write P to LDS (re-shape C-layout -> A-layout) ----
#pragma unroll
        for (int cb = 0; cb < 4; ++cb)
#pragma unroll
            for (int j = 0; j < 4; ++j)
                Pls[w][(lg * 4 + j) * 76 + cb * 16 + lr] = sc[cb][j];
        __syncthreads();

        // ---- PV: O += P @ K  (V == scaled K) ----
#pragma unroll
        for (int kc = 0; kc < 2; ++kc) {
            float ptmp[8];
            *(float4*)&ptmp[0] = *(float4*)&Pls[w][lr * 76 + kc * 32 + lg * 8];
            *(float4*)&ptmp[4] = *(float4*)&Pls[w][lr * 76 + kc * 32 + lg * 8 + 4];
            s8v pA = pack8(ptmp);
#pragma unroll
            for (int db = 0; db < 2; ++db) {
                s8v vB = *(s8v*)&Ktls[(db * 16 + lr) * 88 + kc * 32 + lg * 8];
                accO[db] = __builtin_amdgcn_mfma_f32_16x16x32_bf16(pA, vB, accO[db], 0, 0, 0);
            }
        }
    }

#pragma unroll
    for (int db = 0; db < 2; ++db)
#pragma unroll
        for (int j = 0; j < 4; ++j) {
            int rowg = q0 + lg * 4 + j;
            if (rowg < Nc)
                o[((size_t)b * Nc + rowg) * Cc + h * Dc + db * 16 + lr] = accO[db][j] / lrun[j];
        }
}

__global__ void write_out_kernel(const float* __restrict__ xq, float* __restrict__ out)
{
    int idx = blockIdx.x * 256 + threadIdx.x;
    const int SP = Bc * HWc * Cc;
    if (idx < SP) {
        int c  = idx & (Cc - 1);
        int sp = idx >> 8;
        int hw = sp % HWc;
        int b  = sp / HWc;
        out[idx] = xq[((size_t)b * Nc + NQc + hw) * Cc + c];
    } else if (idx < SP + Bc * NQc * Cc) {
        int j = idx - SP;
        int c = j & (Cc - 1);
        int t2 = j >> 8;
        int n = t2 & (NQc - 1);
        int b = t2 >> 3;
        out[idx] = xq[((size_t)b * Nc + n) * Cc + c];
    }
}

extern "C" void kernel_launch(void* const* d_in, const int* in_sizes, int n_in,
                              void* d_out, int out_size, void* d_ws, size_t ws_size,
                              hipStream_t stream)
{
    const float* x       = (const float*)d_in[0];
    const float* queries = (const float*)d_in[1];
    const int*   epoch   = (const int*)d_in[2];
    const float* pos_w   = (const float*)d_in[3];
    const float* pos_b   = (const float*)d_in[4];
    const float* ln1_g   = (const float*)d_in[5];
    const float* ln1_b   = (const float*)d_in[6];
    const float* q_w     = (const float*)d_in[7];
    const float* q_b     = (const float*)d_in[8];
    const float* k_w     = (const float*)d_in[9];
    const float* k_b     = (const float*)d_in[10];
    const float* v_w     = (const float*)d_in[11];
    const float* v_b     = (const float*)d_in[12];
    const float* lepe_w  = (const float*)d_in[13];
    const float* lepe_b  = (const float*)d_in[14];
    const float* out_w   = (const float*)d_in[15];
    const float* out_b   = (const float*)d_in[16];
    const float* ln2_g   = (const float*)d_in[17];
    const float* ln2_b   = (const float*)d_in[18];
    const float* fc1_w   = (const float*)d_in[19];
    const float* fc1_b   = (const float*)d_in[20];
    const float* fc2_w   = (const float*)d_in[21];
    const float* fc2_b   = (const float*)d_in[22];

    float* ws   = (float*)d_ws;
    float* xq   = ws;                  // 2367488
    float* y    = ws + 2367488;        // 2367488
    float* qb   = ws + 4734976;        // 2367488
    float* kb   = ws + 7102464;        // 2367488
    float* vb   = ws + 9469952;        // 2367488
    float* ob   = ws + 11837440;       // 2367488
    float* pbuf = ws + 14204928;       // 73728
    float* ffn  = qb;                  // fc1 act reuses q/k/v/o region

    const float kscale = 0.17677669529663687f; // (256/8)^-0.5

    pos_conv_kernel<<<9216, 256, 0, stream>>>(x, pos_w, pos_b, xq);
    fill_queries_kernel<<<32, 256, 0, stream>>>(queries, xq);
    region_p_kernel<<<2304, 256, 0, stream>>>(xq, queries, epoch, pbuf);
    ln_kernel<<<2312, 256, 0, stream>>>(xq, ln1_g, ln1_b, y, MRc);

    dim3 g256(4, 145);
    gemm_kernel<0><<<g256, 256, 0, stream>>>(y, q_w, q_b, nullptr, qb, MRc, 256, 256, 1.0f);
    gemm_kernel<0><<<g256, 256, 0, stream>>>(y, k_w, k_b, nullptr, kb, MRc, 256, 256, kscale);
    gemm_kernel<0><<<g256, 256, 0, stream>>>(y, v_w, v_b, nullptr, vb, MRc, 256, 256, 1.0f);

    attn_mfma_kernel<<<dim3(37, 8, 4), 256, 0, stream>>>(qb, kb, pbuf, ob);
    lepe_conv_add_kernel<<<9216, 256, 0, stream>>>(vb, lepe_w, lepe_b, ob);

    gemm_kernel<0><<<g256, 256, 0, stream>>>(ob, out_w, out_b, xq, xq, MRc, 256, 256, 1.0f);

    ln_kernel<<<2312, 256, 0, stream>>>(xq, ln2_g, ln2_b, y, MRc);
    gemm_kernel<1><<<dim3(16, 145), 256, 0, stream>>>(y, fc1_w, fc1_b, nullptr, ffn, MRc, 1024, 256, 1.0f);
    gemm_kernel<0><<<g256, 256, 0, stream>>>(ffn, fc2_w, fc2_b, xq, xq, MRc, 256, 1024, 1.0f);

    write_out_kernel<<<9248, 256, 0, stream>>>(xq, (float*)d_out);
}

// Round 4
// 438.186 us; speedup vs baseline: 3.6451x; 1.3000x over previous
//
#include <hip/hip_runtime.h>
#include <hip/hip_bf16.h>
#include <math.h>

typedef unsigned short u16;
constexpr int Bc = 4, Hc = 48, Wc = 48, Cc = 256;
constexpr int NQc = 8, HWc = 2304, Nc = 2312, NHc = 8, Dc = 32, FFNc = 1024;
constexpr int MRc = Bc * Nc; // 9248
constexpr int KTLDc = 2368;  // padded kv length for transposed K

typedef __attribute__((ext_vector_type(8))) short s8v;
typedef __attribute__((ext_vector_type(4))) float f32x4;

__device__ __forceinline__ u16 f2bf(float f) {
    union { __hip_bfloat16 h; u16 u; } c;
    c.h = __float2bfloat16(f);
    return c.u;
}
__device__ __forceinline__ float bf2f(u16 u) {
    return __uint_as_float(((unsigned)u) << 16);
}
__device__ __forceinline__ s8v pack8(const float* v) {
    union { u16 u[8]; s8v s; } r;
#pragma unroll
    for (int i = 0; i < 8; ++i) r.u[i] = f2bf(v[i]);
    return r.s;
}

// ---------------- weight f32 -> bf16 conversion (one kernel, all 6 weights) ----------------
__global__ void convert_weights_kernel(const float* __restrict__ qw, const float* __restrict__ kw,
                                       const float* __restrict__ vw, const float* __restrict__ ow,
                                       const float* __restrict__ f1, const float* __restrict__ f2,
                                       u16* __restrict__ wbf)
{
    int i4 = blockIdx.x * 256 + threadIdx.x;   // 196608 quads
    if (i4 >= 196608) return;
    int idx = i4 * 4;
    const float* src; int off;
    if      (idx < 65536)  { src = qw; off = idx; }
    else if (idx < 131072) { src = kw; off = idx - 65536; }
    else if (idx < 196608) { src = vw; off = idx - 131072; }
    else if (idx < 262144) { src = ow; off = idx - 196608; }
    else if (idx < 524288) { src = f1; off = idx - 262144; }
    else                   { src = f2; off = idx - 524288; }
    float4 v = *(const float4*)(src + off);
    ushort4 o;
    o.x = f2bf(v.x); o.y = f2bf(v.y); o.z = f2bf(v.z); o.w = f2bf(v.w);
    *(ushort4*)(wbf + idx) = o;
}

// ---------------- zero the kv-pad columns of kt ----------------
__global__ void zero_ktpad_kernel(u16* __restrict__ kt)
{
    int idx = blockIdx.x * 256 + threadIdx.x;  // 1024 rows * 56 pad cols
    if (idx >= 1024 * 56) return;
    int row = idx / 56, col = idx - row * 56;
    kt[(size_t)row * KTLDc + 2312 + col] = 0;
}

// ---------------- pos dwconv 3x3 + residual -> xq spatial rows ----------------
__global__ void pos_conv_kernel(const float* __restrict__ x, const float* __restrict__ w,
                                const float* __restrict__ bias, float* __restrict__ xq)
{
    int idx = blockIdx.x * 256 + threadIdx.x;
    if (idx >= Bc * Hc * Wc * Cc) return;
    int c  = idx & (Cc - 1);
    int sp = idx >> 8;
    int ww = sp % Wc;
    int t2 = sp / Wc;
    int hh = t2 % Hc;
    int b  = t2 / Hc;
    float acc = bias[c];
    float center = x[idx];
#pragma unroll
    for (int kh = 0; kh < 3; ++kh) {
        int yy = hh + kh - 1;
        if (yy < 0 || yy >= Hc) continue;
#pragma unroll
        for (int kw = 0; kw < 3; ++kw) {
            int xx = ww + kw - 1;
            if (xx < 0 || xx >= Wc) continue;
            acc += x[((b * Hc + yy) * Wc + xx) * Cc + c] * w[(kh * 3 + kw) * Cc + c];
        }
    }
    xq[((size_t)b * Nc + NQc + hh * Wc + ww) * Cc + c] = center + acc;
}

__global__ void fill_queries_kernel(const float* __restrict__ q, float* __restrict__ xq)
{
    int idx = blockIdx.x * 256 + threadIdx.x;
    if (idx >= Bc * NQc * Cc) return;
    int c = idx & (Cc - 1);
    int n = (idx >> 8) & (NQc - 1);
    int b = idx >> 11;
    xq[((size_t)b * Nc + n) * Cc + c] = q[idx];
}

// ---------------- region softmax p = softmax(xf @ queries^T / tau) -> bf16 ----------------
__global__ void region_p_kernel(const float* __restrict__ xq, const float* __restrict__ queries,
                                const int* __restrict__ epoch, u16* __restrict__ pbf)
{
    int gid  = blockIdx.x * blockDim.x + threadIdx.x;
    int wid  = gid >> 6;
    int lane = gid & 63;
    if (wid >= Bc * HWc) return;
    int b = wid / HWc, n = wid - b * HWc;
    const float* xr = xq + ((size_t)b * Nc + NQc + n) * Cc;
    float acc[8] = {0, 0, 0, 0, 0, 0, 0, 0};
    for (int c = lane; c < Cc; c += 64) {
        float xv = xr[c];
#pragma unroll
        for (int qi = 0; qi < 8; ++qi)
            acc[qi] += xv * queries[(b * NQc + qi) * Cc + c];
    }
#pragma unroll
    for (int qi = 0; qi < 8; ++qi) {
        float v = acc[qi];
        for (int off = 32; off; off >>= 1) v += __shfl_xor(v, off);
        acc[qi] = v;
    }
    float tau = 2.0f * powf(0.05f, (float)(*epoch) / 200.0f);
    float it  = 1.0f / tau;
    float mx = -1e30f;
#pragma unroll
    for (int qi = 0; qi < 8; ++qi) mx = fmaxf(mx, acc[qi] * it);
    float s = 0.f, e[8];
#pragma unroll
    for (int qi = 0; qi < 8; ++qi) { e[qi] = expf(acc[qi] * it - mx); s += e[qi]; }
    if (lane < 8) pbf[((size_t)b * HWc + n) * 8 + lane] = f2bf(e[lane] / s);
}

// ---------------- LayerNorm (wave per row of 256) -> bf16 ----------------
__global__ void ln_kernel(const float* __restrict__ in, const float* __restrict__ g,
                          const float* __restrict__ bb, u16* __restrict__ out, int rows)
{
    int gid  = blockIdx.x * blockDim.x + threadIdx.x;
    int wid  = gid >> 6;
    int lane = gid & 63;
    if (wid >= rows) return;
    const float* r = in + (size_t)wid * Cc;
    int c = lane * 4;
    float4 v = *(const float4*)(r + c);
    float s = v.x + v.y + v.z + v.w;
    for (int off = 32; off; off >>= 1) s += __shfl_xor(s, off);
    float mean = s * (1.0f / 256.0f);
    float dx = v.x - mean, dy = v.y - mean, dz = v.z - mean, dw = v.w - mean;
    float ss = dx * dx + dy * dy + dz * dz + dw * dw;
    for (int off = 32; off; off >>= 1) ss += __shfl_xor(ss, off);
    float inv = rsqrtf(ss * (1.0f / 256.0f) + 1e-6f);
    ushort4 o;
    o.x = f2bf(dx * inv * g[c + 0] + bb[c + 0]);
    o.y = f2bf(dy * inv * g[c + 1] + bb[c + 1]);
    o.z = f2bf(dz * inv * g[c + 2] + bb[c + 2]);
    o.w = f2bf(dw * inv * g[c + 3] + bb[c + 3]);
    *(ushort4*)(out + (size_t)wid * Cc + c) = o;
}

// ---------------- MFMA GEMM: out[m,n] = act((A[m,:].W[n,:] + bias[n])*scale) (+resid) ----------------
// A bf16 [M][K], W bf16 [N][K]. OMODE: 0=f32 out, 1=bf16 out, 2=bf16 out + transposed kt out.
template <int ACT, int RESID, int OMODE>
__global__ __launch_bounds__(256) void mfma_gemm_kernel(
    const u16* __restrict__ A, const u16* __restrict__ W,
    const float* __restrict__ bias, const float* resid,
    float* outF, u16* outB, u16* outT,
    int M, int N, int K, float scale)
{
    __shared__ u16 As[64 * 72];
    int t = threadIdx.x;
    int w = t >> 6, l = t & 63, lg = l >> 4, lr = l & 15;
    int m0 = blockIdx.y * 64, n0 = blockIdx.x * 64;
    f32x4 acc[4] = {{0.f,0.f,0.f,0.f},{0.f,0.f,0.f,0.f},{0.f,0.f,0.f,0.f},{0.f,0.f,0.f,0.f}};
    int srow = t >> 2, sseg = (t & 3) * 16;
    for (int k0 = 0; k0 < K; k0 += 64) {
        s8v a0 = {0,0,0,0,0,0,0,0}, a1 = a0;
        int gm = m0 + srow;
        if (gm < M) {
            const u16* ap = A + (size_t)gm * K + k0 + sseg;
            a0 = *(const s8v*)ap;
            a1 = *(const s8v*)(ap + 8);
        }
        __syncthreads();
        *(s8v*)&As[srow * 72 + sseg]     = a0;
        *(s8v*)&As[srow * 72 + sseg + 8] = a1;
        __syncthreads();
#pragma unroll
        for (int kk = 0; kk < 64; kk += 32) {
            s8v aF = *(s8v*)&As[(w * 16 + lr) * 72 + kk + lg * 8];
#pragma unroll
            for (int nf = 0; nf < 4; ++nf) {
                s8v bF = *(const s8v*)&W[(size_t)(n0 + nf * 16 + lr) * K + k0 + kk + lg * 8];
                acc[nf] = __builtin_amdgcn_mfma_f32_16x16x32_bf16(aF, bF, acc[nf], 0, 0, 0);
            }
        }
    }
#pragma unroll
    for (int nf = 0; nf < 4; ++nf) {
        int n = n0 + nf * 16 + lr;
        float bv = bias[n];
#pragma unroll
        for (int r = 0; r < 4; ++r) {
            int m = m0 + w * 16 + lg * 4 + r;
            if (m >= M) continue;
            float v = (acc[nf][r] + bv) * scale;
            if (ACT == 1) v = 0.5f * v * (1.0f + erff(v * 0.70710678118654752f));
            if (RESID) v += resid[(size_t)m * N + n];
            if (OMODE == 0) {
                outF[(size_t)m * N + n] = v;
            } else {
                u16 hv = f2bf(v);
                outB[(size_t)m * N + n] = hv;
                if (OMODE == 2) {
                    unsigned um = (unsigned)m;
                    unsigned bb = um / 2312u;
                    unsigned nr = um - bb * 2312u;
                    outT[((size_t)(bb * NHc + (n >> 5)) * Dc + (n & 31)) * KTLDc + nr] = hv;
                }
            }
        }
    }
}

// ---------------- lepe dwconv 5x5 on v (f32), added into bf16 attention output ----------------
__global__ void lepe_conv_add_kernel(const float* __restrict__ v, const float* __restrict__ w,
                                     const float* __restrict__ bias, u16* __restrict__ o)
{
    int idx = blockIdx.x * 256 + threadIdx.x;
    if (idx >= Bc * HWc * Cc) return;
    int c  = idx & (Cc - 1);
    int sp = idx >> 8;
    int ww = sp % Wc;
    int t2 = sp / Wc;
    int hh = t2 % Hc;
    int b  = t2 / Hc;
    float acc = bias[c];
#pragma unroll
    for (int kh = 0; kh < 5; ++kh) {
        int yy = hh + kh - 2;
        if (yy < 0 || yy >= Hc) continue;
#pragma unroll
        for (int kw = 0; kw < 5; ++kw) {
            int xx = ww + kw - 2;
            if (xx < 0 || xx >= Wc) continue;
            acc += v[((size_t)b * Nc + NQc + yy * Wc + xx) * Cc + c] * w[(kh * 5 + kw) * Cc + c];
        }
    }
    size_t oi = ((size_t)b * Nc + NQc + hh * Wc + ww) * Cc + c;
    o[oi] = f2bf(bf2f(o[oi]) + acc);
}

// ---------------- MFMA flash attention (vh == scaled k), rank-8 mask via MFMA ----------------
// all-bf16 inputs; kt pre-transposed. block = 4 waves, wave = 16 q-rows, KV tile 64.
__global__ __launch_bounds__(256, 2) void attn_mfma_kernel(const u16* __restrict__ q,
                                                           const u16* __restrict__ k,
                                                           const u16* __restrict__ kt,
                                                           const u16* __restrict__ p,
                                                           u16* __restrict__ o)
{
    constexpr int KT = 64;
    __shared__ u16 Kls[KT * 40];    // [kv][d] bf16
    __shared__ u16 Ktls[32 * 88];   // [d][kv] bf16
    __shared__ u16 Pkls[KT * 8];    // [kv][8] p bf16
    __shared__ float Pls[4][16 * 76]; // per-wave P tile f32

    int b = blockIdx.z, h = blockIdx.y;
    int t = threadIdx.x;
    int w = t >> 6;
    int l = t & 63;
    int lg = l >> 4;
    int lr = l & 15;
    int q0 = blockIdx.x * 64 + w * 16;

    int qrow = q0 + lr;
    int qrc  = qrow < Nc ? qrow : Nc - 1;
    s8v qA = *(const s8v*)&q[((size_t)b * Nc + qrc) * Cc + h * Dc + lg * 8];

    s8v pqA = {0, 0, 0, 0, 0, 0, 0, 0};
    if (lg == 0 && qrow >= NQc && qrow < Nc)
        pqA = *(const s8v*)&p[((size_t)b * HWc + (qrow - NQc)) * 8];

    f32x4 accO[2] = {{0.f, 0.f, 0.f, 0.f}, {0.f, 0.f, 0.f, 0.f}};
    float mrun[4] = {-1e30f, -1e30f, -1e30f, -1e30f};
    float lrun[4] = {0.f, 0.f, 0.f, 0.f};

    int srow = t >> 2;          // K staging: row 0..63
    int sseg = (t & 3) * 8;     // 8 bf16 of d
    int td   = t >> 3;          // Kt staging: d 0..31
    int tks  = (t & 7) * 8;     // 8 bf16 of kv
    int prow = t >> 1, pseg = (t & 1) * 4;

    const u16* ktbase = kt + ((size_t)(b * NHc + h) * Dc + td) * KTLDc;

    for (int m0 = 0; m0 < Nc; m0 += KT) {
        s8v kv8 = {0,0,0,0,0,0,0,0};
        int kvg = m0 + srow;
        if (kvg < Nc)
            kv8 = *(const s8v*)&k[((size_t)b * Nc + kvg) * Cc + h * Dc + sseg];
        s8v kt8 = *(const s8v*)&ktbase[m0 + tks];
        ushort4 p4 = make_ushort4(0, 0, 0, 0);
        if (t < 128) {
            int pg = m0 + prow;
            if (pg >= NQc && pg < Nc)
                p4 = *(const ushort4*)&p[((size_t)b * HWc + (pg - NQc)) * 8 + pseg];
        }
        __syncthreads();  // previous tile fully consumed
        *(s8v*)&Kls[srow * 40 + sseg] = kv8;
        *(s8v*)&Ktls[td * 88 + tks]   = kt8;
        if (t < 128) *(ushort4*)&Pkls[prow * 8 + pseg] = p4;
        __syncthreads();

        // ---- S = (Q K^T) * mask, online softmax ----
        float sc[4][4];
        bool  okc[4];
        float tmax[4] = {-1e30f, -1e30f, -1e30f, -1e30f};
#pragma unroll
        for (int cb = 0; cb < 4; ++cb) {
            s8v kB = *(s8v*)&Kls[(cb * 16 + lr) * 40 + lg * 8];
            f32x4 S = __builtin_amdgcn_mfma_f32_16x16x32_bf16(qA, kB, (f32x4){0.f, 0.f, 0.f, 0.f}, 0, 0, 0);
            s8v pB = {0, 0, 0, 0, 0, 0, 0, 0};
            if (lg == 0) pB = *(s8v*)&Pkls[(cb * 16 + lr) * 8];
            f32x4 Mv = __builtin_amdgcn_mfma_f32_16x16x32_bf16(pqA, pB, (f32x4){0.f, 0.f, 0.f, 0.f}, 0, 0, 0);
            int colg = m0 + cb * 16 + lr;
            okc[cb] = (colg < Nc);
#pragma unroll
            for (int j = 0; j < 4; ++j) {
                int rowg = q0 + lg * 4 + j;
                float mv = (rowg < NQc || colg < NQc) ? 1.f : Mv[j];
                float s = S[j] * mv;
                sc[cb][j] = s;
                if (okc[cb]) tmax[j] = fmaxf(tmax[j], s);
            }
        }
#pragma unroll
        for (int j = 0; j < 4; ++j) {
            float v = tmax[j];
            v = fmaxf(v, __shfl_xor(v, 1));
            v = fmaxf(v, __shfl_xor(v, 2));
            v = fmaxf(v, __shfl_xor(v, 4));
            v = fmaxf(v, __shfl_xor(v, 8));
            float mnew = fmaxf(mrun[j], v);
            float scl  = __expf(mrun[j] - mnew);
            mrun[j] = mnew;
            accO[0][j] *= scl;
            accO[1][j] *= scl;
            lrun[j] *= scl;
        }
        float lsum[4] = {0.f, 0.f, 0.f, 0.f};
#pragma unroll
        for (int cb = 0; cb < 4; ++cb)
#pragma unroll
            for (int j = 0; j < 4; ++j) {
                float ev = okc[cb] ? __expf(sc[cb][j] - mrun[j]) : 0.f;
                sc[cb][j] = ev;
                lsum[j] += ev;
            }
#pragma unroll
        for (int j = 0; j < 4; ++j) {
            float v = lsum[j];
            v += __shfl_xor(v, 1);
            v += __shfl_xor(v, 2);
            v += __shfl_xor(v, 4);
            v += __shfl_xor(v, 8);
            lrun[j] += v;
        }
#pragma unroll
        for (int cb = 0; cb < 4; ++cb)
#pragma unroll
            for (int j = 0; j < 4; ++j)
                Pls[w][(lg * 4 + j) * 76 + cb * 16 + lr] = sc[cb][j];
        __syncthreads();

        // ---- PV: O += P @ V  (V == scaled K, via transposed tile) ----
#pragma unroll
        for (int kc = 0; kc < 2; ++kc) {
            float ptmp[8];
            *(float4*)&ptmp[0] = *(float4*)&Pls[w][lr * 76 + kc * 32 + lg * 8];
            *(float4*)&ptmp[4] = *(float4*)&Pls[w][lr * 76 + kc * 32 + lg * 8 + 4];
            s8v pA = pack8(ptmp);
#pragma unroll
            for (int db = 0; db < 2; ++db) {
                s8v vB = *(s8v*)&Ktls[(db * 16 + lr) * 88 + kc * 32 + lg * 8];
                accO[db] = __builtin_amdgcn_mfma_f32_16x16x32_bf16(pA, vB, accO[db], 0, 0, 0);
            }
        }
    }

#pragma unroll
    for (int db = 0; db < 2; ++db)
#pragma unroll
        for (int j = 0; j < 4; ++j) {
            int rowg = q0 + lg * 4 + j;
            if (rowg < Nc)
                o[((size_t)b * Nc + rowg) * Cc + h * Dc + db * 16 + lr] = f2bf(accO[db][j] / lrun[j]);
        }
}

__global__ void write_out_kernel(const float* __restrict__ xq, float* __restrict__ out)
{
    int idx = blockIdx.x * 256 + threadIdx.x;
    const int SP = Bc * HWc * Cc;
    if (idx < SP) {
        int c  = idx & (Cc - 1);
        int sp = idx >> 8;
        int hw = sp % HWc;
        int b  = sp / HWc;
        out[idx] = xq[((size_t)b * Nc + NQc + hw) * Cc + c];
    } else if (idx < SP + Bc * NQc * Cc) {
        int j = idx - SP;
        int c = j & (Cc - 1);
        int t2 = j >> 8;
        int n = t2 & (NQc - 1);
        int b = t2 >> 3;
        out[idx] = xq[((size_t)b * Nc + n) * Cc + c];
    }
}

extern "C" void kernel_launch(void* const* d_in, const int* in_sizes, int n_in,
                              void* d_out, int out_size, void* d_ws, size_t ws_size,
                              hipStream_t stream)
{
    const float* x       = (const float*)d_in[0];
    const float* queries = (const float*)d_in[1];
    const int*   epoch   = (const int*)d_in[2];
    const float* pos_w   = (const float*)d_in[3];
    const float* pos_b   = (const float*)d_in[4];
    const float* ln1_g   = (const float*)d_in[5];
    const float* ln1_b   = (const float*)d_in[6];
    const float* q_w     = (const float*)d_in[7];
    const float* q_b     = (const float*)d_in[8];
    const float* k_w     = (const float*)d_in[9];
    const float* k_b     = (const float*)d_in[10];
    const float* v_w     = (const float*)d_in[11];
    const float* v_b     = (const float*)d_in[12];
    const float* lepe_w  = (const float*)d_in[13];
    const float* lepe_b  = (const float*)d_in[14];
    const float* out_w   = (const float*)d_in[15];
    const float* out_b   = (const float*)d_in[16];
    const float* ln2_g   = (const float*)d_in[17];
    const float* ln2_b   = (const float*)d_in[18];
    const float* fc1_w   = (const float*)d_in[19];
    const float* fc1_b   = (const float*)d_in[20];
    const float* fc2_w   = (const float*)d_in[21];
    const float* fc2_b   = (const float*)d_in[22];

    float* ws = (float*)d_ws;
    float* xq  = ws;                        // f32, 2,367,488
    float* vb  = ws + 2367488;              // f32, 2,367,488
    u16*  ybf  = (u16*)(ws + 4734976);      // bf16 2,367,488 elems (1,183,744 slots)
    u16*  qbf  = (u16*)(ws + 5918720);      // bf16 2,367,488
    u16*  kbf  = (u16*)(ws + 7102464);      // bf16 2,367,488
    u16*  ktbf = (u16*)(ws + 8286208);      // bf16 4*8*32*2368 = 2,424,832
    u16*  pbf  = (u16*)(ws + 9498624);      // bf16 73,728
    u16*  obf  = (u16*)(ws + 9535488);      // bf16 2,367,488
    u16*  wbf  = (u16*)(ws + 10719232);     // bf16 786,432 (weights)
    u16*  ffn  = qbf;                       // bf16 9,469,952 (aliases qbf..obf, dead by then)

    u16* w_q  = wbf;
    u16* w_k  = wbf + 65536;
    u16* w_v  = wbf + 131072;
    u16* w_o  = wbf + 196608;
    u16* w_f1 = wbf + 262144;
    u16* w_f2 = wbf + 524288;

    const float kscale = 0.17677669529663687f; // (256/8)^-0.5

    convert_weights_kernel<<<768, 256, 0, stream>>>(q_w, k_w, v_w, out_w, fc1_w, fc2_w, wbf);
    zero_ktpad_kernel<<<224, 256, 0, stream>>>(ktbf);
    pos_conv_kernel<<<9216, 256, 0, stream>>>(x, pos_w, pos_b, xq);
    fill_queries_kernel<<<32, 256, 0, stream>>>(queries, xq);
    region_p_kernel<<<2304, 256, 0, stream>>>(xq, queries, epoch, pbf);
    ln_kernel<<<2312, 256, 0, stream>>>(xq, ln1_g, ln1_b, ybf, MRc);

    dim3 g256(4, 145);
    mfma_gemm_kernel<0,0,1><<<g256, 256, 0, stream>>>(ybf, w_q, q_b, nullptr, nullptr, qbf, nullptr, MRc, 256, 256, 1.0f);
    mfma_gemm_kernel<0,0,2><<<g256, 256, 0, stream>>>(ybf, w_k, k_b, nullptr, nullptr, kbf, ktbf, MRc, 256, 256, kscale);
    mfma_gemm_kernel<0,0,0><<<g256, 256, 0, stream>>>(ybf, w_v, v_b, nullptr, vb, nullptr, nullptr, MRc, 256, 256, 1.0f);

    attn_mfma_kernel<<<dim3(37, 8, 4), 256, 0, stream>>>(qbf, kbf, ktbf, pbf, obf);
    lepe_conv_add_kernel<<<9216, 256, 0, stream>>>(vb, lepe_w, lepe_b, obf);

    mfma_gemm_kernel<0,1,0><<<g256, 256, 0, stream>>>(obf, w_o, out_b, xq, xq, nullptr, nullptr, MRc, 256, 256, 1.0f);

    ln_kernel<<<2312, 256, 0, stream>>>(xq, ln2_g, ln2_b, ybf, MRc);
    mfma_gemm_kernel<1,0,1><<<dim3(16, 145), 256, 0, stream>>>(ybf, w_f1, fc1_b, nullptr, nullptr, ffn, nullptr, MRc, 1024, 256, 1.0f);
    mfma_gemm_kernel<0,1,0><<<g256, 256, 0, stream>>>(ffn, w_f2, fc2_b, xq, xq, nullptr, nullptr, MRc, 256, 1024, 1.0f);

    write_out_kernel<<<9248, 256, 0, stream>>>(xq, (float*)d_out);
}

// Round 5
// 396.670 us; speedup vs baseline: 4.0266x; 1.1047x over previous
//
#include <hip/hip_runtime.h>
#include <hip/hip_bf16.h>
#include <math.h>

typedef unsigned short u16;
constexpr int Bc = 4, Hc = 48, Wc = 48, Cc = 256;
constexpr int NQc = 8, HWc = 2304, Nc = 2312, NHc = 8, Dc = 32, FFNc = 1024;
constexpr int MRc = Bc * Nc; // 9248
constexpr int KTLDc = 2368;  // padded kv length for transposed K

typedef __attribute__((ext_vector_type(8))) short s8v;
typedef __attribute__((ext_vector_type(4))) float f32x4;

__device__ __forceinline__ u16 f2bf(float f) {
    union { __hip_bfloat16 h; u16 u; } c;
    c.h = __float2bfloat16(f);
    return c.u;
}
__device__ __forceinline__ float bf2f(u16 u) {
    return __uint_as_float(((unsigned)u) << 16);
}
__device__ __forceinline__ unsigned pack2(float a, float b) {
    return ((unsigned)f2bf(b) << 16) | (unsigned)f2bf(a);
}

// ---------------- weight f32 -> bf16 conversion ----------------
__global__ void convert_weights_kernel(const float* __restrict__ qw, const float* __restrict__ kw,
                                       const float* __restrict__ vw, const float* __restrict__ ow,
                                       const float* __restrict__ f1, const float* __restrict__ f2,
                                       u16* __restrict__ wbf)
{
    int i4 = blockIdx.x * 256 + threadIdx.x;   // 196608 quads
    if (i4 >= 196608) return;
    int idx = i4 * 4;
    const float* src; int off;
    if      (idx < 65536)  { src = qw; off = idx; }
    else if (idx < 131072) { src = kw; off = idx - 65536; }
    else if (idx < 196608) { src = vw; off = idx - 131072; }
    else if (idx < 262144) { src = ow; off = idx - 196608; }
    else if (idx < 524288) { src = f1; off = idx - 262144; }
    else                   { src = f2; off = idx - 524288; }
    float4 v = *(const float4*)(src + off);
    ushort4 o;
    o.x = f2bf(v.x); o.y = f2bf(v.y); o.z = f2bf(v.z); o.w = f2bf(v.w);
    *(ushort4*)(wbf + idx) = o;
}

// ---------------- zero the kv-pad columns of kt ----------------
__global__ void zero_ktpad_kernel(u16* __restrict__ kt)
{
    int idx = blockIdx.x * 256 + threadIdx.x;  // 1024 rows * 56 pad cols
    if (idx >= 1024 * 56) return;
    int row = idx / 56, col = idx - row * 56;
    kt[(size_t)row * KTLDc + 2312 + col] = 0;
}

// ---------------- pos dwconv 3x3 + residual -> xq spatial rows ----------------
__global__ void pos_conv_kernel(const float* __restrict__ x, const float* __restrict__ w,
                                const float* __restrict__ bias, float* __restrict__ xq)
{
    int idx = blockIdx.x * 256 + threadIdx.x;
    if (idx >= Bc * Hc * Wc * Cc) return;
    int c  = idx & (Cc - 1);
    int sp = idx >> 8;
    int ww = sp % Wc;
    int t2 = sp / Wc;
    int hh = t2 % Hc;
    int b  = t2 / Hc;
    float acc = bias[c];
    float center = x[idx];
#pragma unroll
    for (int kh = 0; kh < 3; ++kh) {
        int yy = hh + kh - 1;
        if (yy < 0 || yy >= Hc) continue;
#pragma unroll
        for (int kw = 0; kw < 3; ++kw) {
            int xx = ww + kw - 1;
            if (xx < 0 || xx >= Wc) continue;
            acc += x[((b * Hc + yy) * Wc + xx) * Cc + c] * w[(kh * 3 + kw) * Cc + c];
        }
    }
    xq[((size_t)b * Nc + NQc + hh * Wc + ww) * Cc + c] = center + acc;
}

__global__ void fill_queries_kernel(const float* __restrict__ q, float* __restrict__ xq)
{
    int idx = blockIdx.x * 256 + threadIdx.x;
    if (idx >= Bc * NQc * Cc) return;
    int c = idx & (Cc - 1);
    int n = (idx >> 8) & (NQc - 1);
    int b = idx >> 11;
    xq[((size_t)b * Nc + n) * Cc + c] = q[idx];
}

// ---------------- region softmax p = softmax(xf @ queries^T / tau) -> bf16 ----------------
__global__ void region_p_kernel(const float* __restrict__ xq, const float* __restrict__ queries,
                                const int* __restrict__ epoch, u16* __restrict__ pbf)
{
    int gid  = blockIdx.x * blockDim.x + threadIdx.x;
    int wid  = gid >> 6;
    int lane = gid & 63;
    if (wid >= Bc * HWc) return;
    int b = wid / HWc, n = wid - b * HWc;
    const float* xr = xq + ((size_t)b * Nc + NQc + n) * Cc;
    float acc[8] = {0, 0, 0, 0, 0, 0, 0, 0};
    for (int c = lane; c < Cc; c += 64) {
        float xv = xr[c];
#pragma unroll
        for (int qi = 0; qi < 8; ++qi)
            acc[qi] += xv * queries[(b * NQc + qi) * Cc + c];
    }
#pragma unroll
    for (int qi = 0; qi < 8; ++qi) {
        float v = acc[qi];
        for (int off = 32; off; off >>= 1) v += __shfl_xor(v, off);
        acc[qi] = v;
    }
    float tau = 2.0f * powf(0.05f, (float)(*epoch) / 200.0f);
    float it  = 1.0f / tau;
    float mx = -1e30f;
#pragma unroll
    for (int qi = 0; qi < 8; ++qi) mx = fmaxf(mx, acc[qi] * it);
    float s = 0.f, e[8];
#pragma unroll
    for (int qi = 0; qi < 8; ++qi) { e[qi] = expf(acc[qi] * it - mx); s += e[qi]; }
    if (lane < 8) pbf[((size_t)b * HWc + n) * 8 + lane] = f2bf(e[lane] / s);
}

// ---------------- LayerNorm (wave per row of 256) -> bf16 ----------------
__global__ void ln_kernel(const float* __restrict__ in, const float* __restrict__ g,
                          const float* __restrict__ bb, u16* __restrict__ out, int rows)
{
    int gid  = blockIdx.x * blockDim.x + threadIdx.x;
    int wid  = gid >> 6;
    int lane = gid & 63;
    if (wid >= rows) return;
    const float* r = in + (size_t)wid * Cc;
    int c = lane * 4;
    float4 v = *(const float4*)(r + c);
    float s = v.x + v.y + v.z + v.w;
    for (int off = 32; off; off >>= 1) s += __shfl_xor(s, off);
    float mean = s * (1.0f / 256.0f);
    float dx = v.x - mean, dy = v.y - mean, dz = v.z - mean, dw = v.w - mean;
    float ss = dx * dx + dy * dy + dz * dz + dw * dw;
    for (int off = 32; off; off >>= 1) ss += __shfl_xor(ss, off);
    float inv = rsqrtf(ss * (1.0f / 256.0f) + 1e-6f);
    ushort4 o;
    o.x = f2bf(dx * inv * g[c + 0] + bb[c + 0]);
    o.y = f2bf(dy * inv * g[c + 1] + bb[c + 1]);
    o.z = f2bf(dz * inv * g[c + 2] + bb[c + 2]);
    o.w = f2bf(dw * inv * g[c + 3] + bb[c + 3]);
    *(ushort4*)(out + (size_t)wid * Cc + c) = o;
}

// ---------------- MFMA GEMM: out[m,n] = act((A[m,:].W[n,:] + bias[n])*scale) (+resid) ----------------
// OMODE: 0=f32 out, 1=bf16 out, 2=bf16 out + transposed kt out, 3=f32 out permuted to d_out layout (N==256)
template <int ACT, int RESID, int OMODE>
__global__ __launch_bounds__(256) void mfma_gemm_kernel(
    const u16* __restrict__ A, const u16* __restrict__ W,
    const float* __restrict__ bias, const float* resid,
    float* outF, u16* outB, u16* outT,
    int M, int N, int K, float scale)
{
    __shared__ u16 As[64 * 72];
    int t = threadIdx.x;
    int w = t >> 6, l = t & 63, lg = l >> 4, lr = l & 15;
    int m0 = blockIdx.y * 64, n0 = blockIdx.x * 64;
    f32x4 acc[4] = {{0.f,0.f,0.f,0.f},{0.f,0.f,0.f,0.f},{0.f,0.f,0.f,0.f},{0.f,0.f,0.f,0.f}};
    int srow = t >> 2, sseg = (t & 3) * 16;
    for (int k0 = 0; k0 < K; k0 += 64) {
        s8v a0 = {0,0,0,0,0,0,0,0}, a1 = a0;
        int gm = m0 + srow;
        if (gm < M) {
            const u16* ap = A + (size_t)gm * K + k0 + sseg;
            a0 = *(const s8v*)ap;
            a1 = *(const s8v*)(ap + 8);
        }
        __syncthreads();
        *(s8v*)&As[srow * 72 + sseg]     = a0;
        *(s8v*)&As[srow * 72 + sseg + 8] = a1;
        __syncthreads();
#pragma unroll
        for (int kk = 0; kk < 64; kk += 32) {
            s8v aF = *(s8v*)&As[(w * 16 + lr) * 72 + kk + lg * 8];
#pragma unroll
            for (int nf = 0; nf < 4; ++nf) {
                s8v bF = *(const s8v*)&W[(size_t)(n0 + nf * 16 + lr) * K + k0 + kk + lg * 8];
                acc[nf] = __builtin_amdgcn_mfma_f32_16x16x32_bf16(aF, bF, acc[nf], 0, 0, 0);
            }
        }
    }
    size_t obase[4];
    if (OMODE == 3) {
#pragma unroll
        for (int r = 0; r < 4; ++r) {
            int m = m0 + w * 16 + lg * 4 + r;
            if (m >= M) { obase[r] = 0; continue; }
            unsigned bb2 = (unsigned)m / 2312u;
            unsigned tok = (unsigned)m - bb2 * 2312u;
            obase[r] = (tok >= 8) ? (((size_t)(bb2 * 2304 + tok - 8)) << 8)
                                  : ((size_t)2359296 + (((size_t)(bb2 * 8 + tok)) << 8));
        }
    }
#pragma unroll
    for (int nf = 0; nf < 4; ++nf) {
        int n = n0 + nf * 16 + lr;
        float bv = bias[n];
#pragma unroll
        for (int r = 0; r < 4; ++r) {
            int m = m0 + w * 16 + lg * 4 + r;
            if (m >= M) continue;
            float v = (acc[nf][r] + bv) * scale;
            if (ACT == 1) v = 0.5f * v * (1.0f + erff(v * 0.70710678118654752f));
            if (RESID) v += resid[(size_t)m * N + n];
            if (OMODE == 0) {
                outF[(size_t)m * N + n] = v;
            } else if (OMODE == 3) {
                outF[obase[r] + n] = v;
            } else {
                u16 hv = f2bf(v);
                outB[(size_t)m * N + n] = hv;
                if (OMODE == 2) {
                    unsigned um = (unsigned)m;
                    unsigned bb = um / 2312u;
                    unsigned nr = um - bb * 2312u;
                    outT[((size_t)(bb * NHc + (n >> 5)) * Dc + (n & 31)) * KTLDc + nr] = hv;
                }
            }
        }
    }
}

// ---------------- lepe dwconv 5x5 on v (f32), added into bf16 attention output ----------------
__global__ void lepe_conv_add_kernel(const float* __restrict__ v, const float* __restrict__ w,
                                     const float* __restrict__ bias, u16* __restrict__ o)
{
    int idx = blockIdx.x * 256 + threadIdx.x;
    if (idx >= Bc * HWc * Cc) return;
    int c  = idx & (Cc - 1);
    int sp = idx >> 8;
    int ww = sp % Wc;
    int t2 = sp / Wc;
    int hh = t2 % Hc;
    int b  = t2 / Hc;
    float acc = bias[c];
#pragma unroll
    for (int kh = 0; kh < 5; ++kh) {
        int yy = hh + kh - 2;
        if (yy < 0 || yy >= Hc) continue;
#pragma unroll
        for (int kw = 0; kw < 5; ++kw) {
            int xx = ww + kw - 2;
            if (xx < 0 || xx >= Wc) continue;
            acc += v[((size_t)b * Nc + NQc + yy * Wc + xx) * Cc + c] * w[(kh * 5 + kw) * Cc + c];
        }
    }
    size_t oi = ((size_t)b * Nc + NQc + hh * Wc + ww) * Cc + c;
    o[oi] = f2bf(bf2f(o[oi]) + acc);
}

// ---------------- MFMA flash attention, swapped QK^T (lane owns one q-row) ----------------
// S^T = mfma(K, Q); softmax per-lane; P packed bf16 -> per-wave LDS -> A-frag for PV.
__global__ __launch_bounds__(256, 2) void attn_mfma_kernel(const u16* __restrict__ q,
                                                           const u16* __restrict__ k,
                                                           const u16* __restrict__ kt,
                                                           const u16* __restrict__ p,
                                                           u16* __restrict__ o)
{
    constexpr int KT = 64;
    __shared__ __align__(16) u16 Kls[KT * 40];     // [kv][d]
    __shared__ __align__(16) u16 Ktls[32 * 88];    // [d][kv]
    __shared__ __align__(16) u16 Pkls[KT * 8];     // [kv][8]
    __shared__ __align__(16) unsigned PW[4][16 * 36]; // per-wave packed P: [q-row][kv/2 u32]

    int b = blockIdx.z, h = blockIdx.y;
    int t = threadIdx.x;
    int w = t >> 6, l = t & 63, lg = l >> 4, lr = l & 15;
    int q0 = blockIdx.x * 64 + w * 16;

    int qrow = q0 + lr;
    bool qtok = (qrow < NQc);
    int qrc = qrow < Nc ? qrow : Nc - 1;
    s8v qB = *(const s8v*)&q[((size_t)b * Nc + qrc) * Cc + h * Dc + lg * 8];

    s8v pqB = {0, 0, 0, 0, 0, 0, 0, 0};
    if (lg == 0 && qrow >= NQc && qrow < Nc)
        pqB = *(const s8v*)&p[((size_t)b * HWc + (qrow - NQc)) * 8];

    f32x4 accO[2] = {{0.f, 0.f, 0.f, 0.f}, {0.f, 0.f, 0.f, 0.f}};
    float mrun = -1e30f, lrun = 0.f;

    int srow = t >> 2, sseg = (t & 3) * 8;     // K staging
    int td = t >> 3, tks = (t & 7) * 8;        // Kt staging
    int prow = t >> 1, pseg = (t & 1) * 4;     // p staging
    const u16* ktbase = kt + ((size_t)(b * NHc + h) * Dc + td) * KTLDc;
    unsigned swz = (lr & 7) << 2;
    unsigned* PWr = &PW[w][lr * 36];
    int bsrc = lg * 20;  // broadcast source lane base (lr == lg*4+j lives there)

    for (int m0 = 0; m0 < Nc; m0 += KT) {
        bool tail = (m0 + KT > Nc);
        // ---- stage K / Kt / p tiles ----
        s8v kv8 = {0,0,0,0,0,0,0,0};
        int kvg = m0 + srow;
        if (kvg < Nc)
            kv8 = *(const s8v*)&k[((size_t)b * Nc + kvg) * Cc + h * Dc + sseg];
        s8v kt8 = *(const s8v*)&ktbase[m0 + tks];
        ushort4 p4 = make_ushort4(0, 0, 0, 0);
        if (t < 128) {
            int pg = m0 + prow;
            if (pg >= NQc && pg < Nc)
                p4 = *(const ushort4*)&p[((size_t)b * HWc + (pg - NQc)) * 8 + pseg];
        }
        __syncthreads();  // previous tile fully consumed
        *(s8v*)&Kls[srow * 40 + sseg] = kv8;
        *(s8v*)&Ktls[td * 88 + tks]   = kt8;
        if (t < 128) *(ushort4*)&Pkls[prow * 8 + pseg] = p4;
        __syncthreads();

        // ---- S^T tiles: mfma(K, Q); mask via mfma(pk, pq) ----
        float sc[4][4];
#pragma unroll
        for (int cb = 0; cb < 4; ++cb) {
            s8v kA = *(s8v*)&Kls[(cb * 16 + lr) * 40 + lg * 8];
            f32x4 St = __builtin_amdgcn_mfma_f32_16x16x32_bf16(kA, qB, (f32x4){0.f,0.f,0.f,0.f}, 0, 0, 0);
            s8v pkA = {0, 0, 0, 0, 0, 0, 0, 0};
            if (lg == 0) pkA = *(s8v*)&Pkls[(cb * 16 + lr) * 8];
            f32x4 Mv = __builtin_amdgcn_mfma_f32_16x16x32_bf16(pkA, pqB, (f32x4){0.f,0.f,0.f,0.f}, 0, 0, 0);
            bool ktok = (m0 == 0 && cb == 0 && lg < 2);  // kv-row < 8
#pragma unroll
            for (int j = 0; j < 4; ++j) {
                float mval = (qtok || ktok) ? 1.f : Mv[j];
                sc[cb][j] = St[j] * mval;
            }
        }
        // ---- online softmax, per-lane q-row ----
        float tmax = sc[0][0];
#pragma unroll
        for (int cb = 0; cb < 4; ++cb)
#pragma unroll
            for (int j = 0; j < 4; ++j) tmax = fmaxf(tmax, sc[cb][j]);
        tmax = fmaxf(tmax, __shfl_xor(tmax, 16));
        tmax = fmaxf(tmax, __shfl_xor(tmax, 32));
        float mnew = fmaxf(mrun, tmax);
        float scl = __expf(mrun - mnew);
        mrun = mnew;
        lrun *= scl;
        float sb0 = __shfl(scl, bsrc + 0);
        float sb1 = __shfl(scl, bsrc + 1);
        float sb2 = __shfl(scl, bsrc + 2);
        float sb3 = __shfl(scl, bsrc + 3);
        accO[0][0] *= sb0; accO[1][0] *= sb0;
        accO[0][1] *= sb1; accO[1][1] *= sb1;
        accO[0][2] *= sb2; accO[1][2] *= sb2;
        accO[0][3] *= sb3; accO[1][3] *= sb3;
        float tsum = 0.f;
#pragma unroll
        for (int cb = 0; cb < 4; ++cb)
#pragma unroll
            for (int j = 0; j < 4; ++j) {
                float ev = __expf(sc[cb][j] - mnew);
                if (tail && (cb != 0 || lg >= 2)) ev = 0.f;  // kv >= Nc
                sc[cb][j] = ev;
                tsum += ev;
            }
        tsum += __shfl_xor(tsum, 16);
        tsum += __shfl_xor(tsum, 32);
        lrun += tsum;
        // ---- pack P (bf16 pairs) into per-wave LDS ----
#pragma unroll
        for (int cb = 0; cb < 4; ++cb) {
            uint2 pk2;
            pk2.x = pack2(sc[cb][0], sc[cb][1]);
            pk2.y = pack2(sc[cb][2], sc[cb][3]);
            *(uint2*)&PWr[(unsigned)(8 * cb + 2 * lg) ^ swz] = pk2;
        }
        // ---- PV: O += P @ V (V == scaled K via transposed tile); per-wave, no barrier ----
#pragma unroll
        for (int kc = 0; kc < 2; ++kc) {
            s8v pA = *(s8v*)&PWr[(unsigned)(16 * kc + 4 * lg) ^ swz];
#pragma unroll
            for (int db = 0; db < 2; ++db) {
                s8v vB = *(s8v*)&Ktls[(db * 16 + lr) * 88 + kc * 32 + lg * 8];
                accO[db] = __builtin_amdgcn_mfma_f32_16x16x32_bf16(pA, vB, accO[db], 0, 0, 0);
            }
        }
    }

    float lb[4];
#pragma unroll
    for (int j = 0; j < 4; ++j) lb[j] = __shfl(lrun, bsrc + j);
#pragma unroll
    for (int db = 0; db < 2; ++db)
#pragma unroll
        for (int j = 0; j < 4; ++j) {
            int rowg = q0 + lg * 4 + j;
            if (rowg < Nc)
                o[((size_t)b * Nc + rowg) * Cc + h * Dc + db * 16 + lr] = f2bf(accO[db][j] / lb[j]);
        }
}

extern "C" void kernel_launch(void* const* d_in, const int* in_sizes, int n_in,
                              void* d_out, int out_size, void* d_ws, size_t ws_size,
                              hipStream_t stream)
{
    const float* x       = (const float*)d_in[0];
    const float* queries = (const float*)d_in[1];
    const int*   epoch   = (const int*)d_in[2];
    const float* pos_w   = (const float*)d_in[3];
    const float* pos_b   = (const float*)d_in[4];
    const float* ln1_g   = (const float*)d_in[5];
    const float* ln1_b   = (const float*)d_in[6];
    const float* q_w     = (const float*)d_in[7];
    const float* q_b     = (const float*)d_in[8];
    const float* k_w     = (const float*)d_in[9];
    const float* k_b     = (const float*)d_in[10];
    const float* v_w     = (const float*)d_in[11];
    const float* v_b     = (const float*)d_in[12];
    const float* lepe_w  = (const float*)d_in[13];
    const float* lepe_b  = (const float*)d_in[14];
    const float* out_w   = (const float*)d_in[15];
    const float* out_b   = (const float*)d_in[16];
    const float* ln2_g   = (const float*)d_in[17];
    const float* ln2_b   = (const float*)d_in[18];
    const float* fc1_w   = (const float*)d_in[19];
    const float* fc1_b   = (const float*)d_in[20];
    const float* fc2_w   = (const float*)d_in[21];
    const float* fc2_b   = (const float*)d_in[22];

    float* ws = (float*)d_ws;
    float* xq  = ws;                        // f32, 2,367,488
    float* vb  = ws + 2367488;              // f32, 2,367,488
    u16*  ybf  = (u16*)(ws + 4734976);      // bf16 2,367,488
    u16*  qbf  = (u16*)(ws + 5918720);      // bf16 2,367,488
    u16*  kbf  = (u16*)(ws + 7102464);      // bf16 2,367,488
    u16*  ktbf = (u16*)(ws + 8286208);      // bf16 4*8*32*2368 = 2,424,832
    u16*  pbf  = (u16*)(ws + 9498624);      // bf16 73,728
    u16*  obf  = (u16*)(ws + 9535488);      // bf16 2,367,488
    u16*  wbf  = (u16*)(ws + 10719232);     // bf16 786,432 (weights)
    u16*  ffn  = qbf;                       // bf16 9,469,952 (aliases qbf..obf, dead by then)

    u16* w_q  = wbf;
    u16* w_k  = wbf + 65536;
    u16* w_v  = wbf + 131072;
    u16* w_o  = wbf + 196608;
    u16* w_f1 = wbf + 262144;
    u16* w_f2 = wbf + 524288;

    const float kscale = 0.17677669529663687f; // (256/8)^-0.5

    convert_weights_kernel<<<768, 256, 0, stream>>>(q_w, k_w, v_w, out_w, fc1_w, fc2_w, wbf);
    zero_ktpad_kernel<<<224, 256, 0, stream>>>(ktbf);
    pos_conv_kernel<<<9216, 256, 0, stream>>>(x, pos_w, pos_b, xq);
    fill_queries_kernel<<<32, 256, 0, stream>>>(queries, xq);
    region_p_kernel<<<2304, 256, 0, stream>>>(xq, queries, epoch, pbf);
    ln_kernel<<<2312, 256, 0, stream>>>(xq, ln1_g, ln1_b, ybf, MRc);

    dim3 g256(4, 145);
    mfma_gemm_kernel<0,0,1><<<g256, 256, 0, stream>>>(ybf, w_q, q_b, nullptr, nullptr, qbf, nullptr, MRc, 256, 256, 1.0f);
    mfma_gemm_kernel<0,0,2><<<g256, 256, 0, stream>>>(ybf, w_k, k_b, nullptr, nullptr, kbf, ktbf, MRc, 256, 256, kscale);
    mfma_gemm_kernel<0,0,0><<<g256, 256, 0, stream>>>(ybf, w_v, v_b, nullptr, vb, nullptr, nullptr, MRc, 256, 256, 1.0f);

    attn_mfma_kernel<<<dim3(37, 8, 4), 256, 0, stream>>>(qbf, kbf, ktbf, pbf, obf);
    lepe_conv_add_kernel<<<9216, 256, 0, stream>>>(vb, lepe_w, lepe_b, obf);

    mfma_gemm_kernel<0,1,0><<<g256, 256, 0, stream>>>(obf, w_o, out_b, xq, xq, nullptr, nullptr, MRc, 256, 256, 1.0f);

    ln_kernel<<<2312, 256, 0, stream>>>(xq, ln2_g, ln2_b, ybf, MRc);
    mfma_gemm_kernel<1,0,1><<<dim3(16, 145), 256, 0, stream>>>(ybf, w_f1, fc1_b, nullptr, nullptr, ffn, nullptr, MRc, 1024, 256, 1.0f);
    mfma_gemm_kernel<0,1,3><<<g256, 256, 0, stream>>>(ffn, w_f2, fc2_b, xq, (float*)d_out, nullptr, nullptr, MRc, 256, 1024, 1.0f);
}

// Round 6
// 358.766 us; speedup vs baseline: 4.4520x; 1.1057x over previous
//
#include <hip/hip_runtime.h>
#include <hip/hip_bf16.h>
#include <math.h>

typedef unsigned short u16;
constexpr int Bc = 4, Hc = 48, Wc = 48, Cc = 256;
constexpr int NQc = 8, HWc = 2304, Nc = 2312, NHc = 8, Dc = 32, FFNc = 1024;
constexpr int MRc = Bc * Nc; // 9248
constexpr int KTLDc = 2368;  // padded kv length for transposed K

typedef __attribute__((ext_vector_type(8))) short s8v;
typedef __attribute__((ext_vector_type(4))) float f32x4;

__device__ __forceinline__ u16 f2bf(float f) {
    union { __hip_bfloat16 h; u16 u; } c;
    c.h = __float2bfloat16(f);
    return c.u;
}
__device__ __forceinline__ float bf2f(u16 u) {
    return __uint_as_float(((unsigned)u) << 16);
}
__device__ __forceinline__ unsigned cvtpk2(float lo, float hi) {
    unsigned r;
    asm("v_cvt_pk_bf16_f32 %0, %1, %2" : "=v"(r) : "v"(lo), "v"(hi));
    return r;
}

// ---------------- weight f32 -> bf16 conversion ----------------
__global__ void convert_weights_kernel(const float* __restrict__ qw, const float* __restrict__ kw,
                                       const float* __restrict__ vw, const float* __restrict__ ow,
                                       const float* __restrict__ f1, const float* __restrict__ f2,
                                       u16* __restrict__ wbf)
{
    int i4 = blockIdx.x * 256 + threadIdx.x;   // 196608 quads
    if (i4 >= 196608) return;
    int idx = i4 * 4;
    const float* src; int off;
    if      (idx < 65536)  { src = qw; off = idx; }
    else if (idx < 131072) { src = kw; off = idx - 65536; }
    else if (idx < 196608) { src = vw; off = idx - 131072; }
    else if (idx < 262144) { src = ow; off = idx - 196608; }
    else if (idx < 524288) { src = f1; off = idx - 262144; }
    else                   { src = f2; off = idx - 524288; }
    float4 v = *(const float4*)(src + off);
    ushort4 o;
    o.x = f2bf(v.x); o.y = f2bf(v.y); o.z = f2bf(v.z); o.w = f2bf(v.w);
    *(ushort4*)(wbf + idx) = o;
}

// ---------------- zero the kv-pad columns of kt ----------------
__global__ void zero_ktpad_kernel(u16* __restrict__ kt)
{
    int idx = blockIdx.x * 256 + threadIdx.x;  // 1024 rows * 56 pad cols
    if (idx >= 1024 * 56) return;
    int row = idx / 56, col = idx - row * 56;
    kt[(size_t)row * KTLDc + 2312 + col] = 0;
}

// ---------------- pos dwconv 3x3 + residual -> xq spatial rows ----------------
__global__ void pos_conv_kernel(const float* __restrict__ x, const float* __restrict__ w,
                                const float* __restrict__ bias, float* __restrict__ xq)
{
    int idx = blockIdx.x * 256 + threadIdx.x;
    if (idx >= Bc * Hc * Wc * Cc) return;
    int c  = idx & (Cc - 1);
    int sp = idx >> 8;
    int ww = sp % Wc;
    int t2 = sp / Wc;
    int hh = t2 % Hc;
    int b  = t2 / Hc;
    float acc = bias[c];
    float center = x[idx];
#pragma unroll
    for (int kh = 0; kh < 3; ++kh) {
        int yy = hh + kh - 1;
        if (yy < 0 || yy >= Hc) continue;
#pragma unroll
        for (int kw = 0; kw < 3; ++kw) {
            int xx = ww + kw - 1;
            if (xx < 0 || xx >= Wc) continue;
            acc += x[((b * Hc + yy) * Wc + xx) * Cc + c] * w[(kh * 3 + kw) * Cc + c];
        }
    }
    xq[((size_t)b * Nc + NQc + hh * Wc + ww) * Cc + c] = center + acc;
}

__global__ void fill_queries_kernel(const float* __restrict__ q, float* __restrict__ xq)
{
    int idx = blockIdx.x * 256 + threadIdx.x;
    if (idx >= Bc * NQc * Cc) return;
    int c = idx & (Cc - 1);
    int n = (idx >> 8) & (NQc - 1);
    int b = idx >> 11;
    xq[((size_t)b * Nc + n) * Cc + c] = q[idx];
}

// ---------------- region softmax p = softmax(xf @ queries^T / tau) -> bf16 ----------------
__global__ void region_p_kernel(const float* __restrict__ xq, const float* __restrict__ queries,
                                const int* __restrict__ epoch, u16* __restrict__ pbf)
{
    int gid  = blockIdx.x * blockDim.x + threadIdx.x;
    int wid  = gid >> 6;
    int lane = gid & 63;
    if (wid >= Bc * HWc) return;
    int b = wid / HWc, n = wid - b * HWc;
    const float* xr = xq + ((size_t)b * Nc + NQc + n) * Cc;
    float acc[8] = {0, 0, 0, 0, 0, 0, 0, 0};
    for (int c = lane; c < Cc; c += 64) {
        float xv = xr[c];
#pragma unroll
        for (int qi = 0; qi < 8; ++qi)
            acc[qi] += xv * queries[(b * NQc + qi) * Cc + c];
    }
#pragma unroll
    for (int qi = 0; qi < 8; ++qi) {
        float v = acc[qi];
        for (int off = 32; off; off >>= 1) v += __shfl_xor(v, off);
        acc[qi] = v;
    }
    float tau = 2.0f * powf(0.05f, (float)(*epoch) / 200.0f);
    float it  = 1.0f / tau;
    float mx = -1e30f;
#pragma unroll
    for (int qi = 0; qi < 8; ++qi) mx = fmaxf(mx, acc[qi] * it);
    float s = 0.f, e[8];
#pragma unroll
    for (int qi = 0; qi < 8; ++qi) { e[qi] = expf(acc[qi] * it - mx); s += e[qi]; }
    if (lane < 8) pbf[((size_t)b * HWc + n) * 8 + lane] = f2bf(e[lane] / s);
}

// ---------------- LayerNorm (wave per row of 256) -> bf16 ----------------
__global__ void ln_kernel(const float* __restrict__ in, const float* __restrict__ g,
                          const float* __restrict__ bb, u16* __restrict__ out, int rows)
{
    int gid  = blockIdx.x * blockDim.x + threadIdx.x;
    int wid  = gid >> 6;
    int lane = gid & 63;
    if (wid >= rows) return;
    const float* r = in + (size_t)wid * Cc;
    int c = lane * 4;
    float4 v = *(const float4*)(r + c);
    float s = v.x + v.y + v.z + v.w;
    for (int off = 32; off; off >>= 1) s += __shfl_xor(s, off);
    float mean = s * (1.0f / 256.0f);
    float dx = v.x - mean, dy = v.y - mean, dz = v.z - mean, dw = v.w - mean;
    float ss = dx * dx + dy * dy + dz * dz + dw * dw;
    for (int off = 32; off; off >>= 1) ss += __shfl_xor(ss, off);
    float inv = rsqrtf(ss * (1.0f / 256.0f) + 1e-6f);
    ushort4 o;
    o.x = f2bf(dx * inv * g[c + 0] + bb[c + 0]);
    o.y = f2bf(dy * inv * g[c + 1] + bb[c + 1]);
    o.z = f2bf(dz * inv * g[c + 2] + bb[c + 2]);
    o.w = f2bf(dw * inv * g[c + 3] + bb[c + 3]);
    *(ushort4*)(out + (size_t)wid * Cc + c) = o;
}

// ---------------- MFMA GEMM: out[m,n] = act((A[m,:].W[n,:] + bias[n])*scale) (+resid) ----------------
// OMODE: 0=f32 out, 1=bf16 out, 2=bf16 out + transposed kt out, 3=f32 out permuted to d_out layout (N==256)
template <int ACT, int RESID, int OMODE>
__global__ __launch_bounds__(256) void mfma_gemm_kernel(
    const u16* __restrict__ A, const u16* __restrict__ W,
    const float* __restrict__ bias, const float* resid,
    float* outF, u16* outB, u16* outT,
    int M, int N, int K, float scale)
{
    __shared__ u16 As[64 * 72];
    int t = threadIdx.x;
    int w = t >> 6, l = t & 63, lg = l >> 4, lr = l & 15;
    int m0 = blockIdx.y * 64, n0 = blockIdx.x * 64;
    f32x4 acc[4] = {{0.f,0.f,0.f,0.f},{0.f,0.f,0.f,0.f},{0.f,0.f,0.f,0.f},{0.f,0.f,0.f,0.f}};
    int srow = t >> 2, sseg = (t & 3) * 16;
    for (int k0 = 0; k0 < K; k0 += 64) {
        s8v a0 = {0,0,0,0,0,0,0,0}, a1 = a0;
        int gm = m0 + srow;
        if (gm < M) {
            const u16* ap = A + (size_t)gm * K + k0 + sseg;
            a0 = *(const s8v*)ap;
            a1 = *(const s8v*)(ap + 8);
        }
        __syncthreads();
        *(s8v*)&As[srow * 72 + sseg]     = a0;
        *(s8v*)&As[srow * 72 + sseg + 8] = a1;
        __syncthreads();
#pragma unroll
        for (int kk = 0; kk < 64; kk += 32) {
            s8v aF = *(s8v*)&As[(w * 16 + lr) * 72 + kk + lg * 8];
#pragma unroll
            for (int nf = 0; nf < 4; ++nf) {
                s8v bF = *(const s8v*)&W[(size_t)(n0 + nf * 16 + lr) * K + k0 + kk + lg * 8];
                acc[nf] = __builtin_amdgcn_mfma_f32_16x16x32_bf16(aF, bF, acc[nf], 0, 0, 0);
            }
        }
    }
    size_t obase[4];
    if (OMODE == 3) {
#pragma unroll
        for (int r = 0; r < 4; ++r) {
            int m = m0 + w * 16 + lg * 4 + r;
            if (m >= M) { obase[r] = 0; continue; }
            unsigned bb2 = (unsigned)m / 2312u;
            unsigned tok = (unsigned)m - bb2 * 2312u;
            obase[r] = (tok >= 8) ? (((size_t)(bb2 * 2304 + tok - 8)) << 8)
                                  : ((size_t)2359296 + (((size_t)(bb2 * 8 + tok)) << 8));
        }
    }
#pragma unroll
    for (int nf = 0; nf < 4; ++nf) {
        int n = n0 + nf * 16 + lr;
        float bv = bias[n];
#pragma unroll
        for (int r = 0; r < 4; ++r) {
            int m = m0 + w * 16 + lg * 4 + r;
            if (m >= M) continue;
            float v = (acc[nf][r] + bv) * scale;
            if (ACT == 1) v = 0.5f * v * (1.0f + erff(v * 0.70710678118654752f));
            if (RESID) v += resid[(size_t)m * N + n];
            if (OMODE == 0) {
                outF[(size_t)m * N + n] = v;
            } else if (OMODE == 3) {
                outF[obase[r] + n] = v;
            } else {
                u16 hv = f2bf(v);
                outB[(size_t)m * N + n] = hv;
                if (OMODE == 2) {
                    unsigned um = (unsigned)m;
                    unsigned bb = um / 2312u;
                    unsigned nr = um - bb * 2312u;
                    outT[((size_t)(bb * NHc + (n >> 5)) * Dc + (n & 31)) * KTLDc + nr] = hv;
                }
            }
        }
    }
}

// ---------------- lepe dwconv 5x5 on v (f32), added into bf16 attention output ----------------
__global__ void lepe_conv_add_kernel(const float* __restrict__ v, const float* __restrict__ w,
                                     const float* __restrict__ bias, u16* __restrict__ o)
{
    int idx = blockIdx.x * 256 + threadIdx.x;
    if (idx >= Bc * HWc * Cc) return;
    int c  = idx & (Cc - 1);
    int sp = idx >> 8;
    int ww = sp % Wc;
    int t2 = sp / Wc;
    int hh = t2 % Hc;
    int b  = t2 / Hc;
    float acc = bias[c];
#pragma unroll
    for (int kh = 0; kh < 5; ++kh) {
        int yy = hh + kh - 2;
        if (yy < 0 || yy >= Hc) continue;
#pragma unroll
        for (int kw = 0; kw < 5; ++kw) {
            int xx = ww + kw - 2;
            if (xx < 0 || xx >= Wc) continue;
            acc += v[((size_t)b * Nc + NQc + yy * Wc + xx) * Cc + c] * w[(kh * 5 + kw) * Cc + c];
        }
    }
    size_t oi = ((size_t)b * Nc + NQc + hh * Wc + ww) * Cc + c;
    o[oi] = f2bf(bf2f(o[oi]) + acc);
}

// ---------------- MFMA flash attention, swapped QK^T (lane owns one q-row) ----------------
// Prefetched staging (T14); conflict-free P buffer (stride 36, no swizzle).
__global__ __launch_bounds__(256, 4) void attn_mfma_kernel(const u16* __restrict__ q,
                                                           const u16* __restrict__ k,
                                                           const u16* __restrict__ kt,
                                                           const u16* __restrict__ p,
                                                           u16* __restrict__ o)
{
    constexpr int KT = 64;
    constexpr int NT = (Nc + KT - 1) / KT;  // 37
    __shared__ __align__(16) u16 Kls[KT * 40];     // [kv][d]
    __shared__ __align__(16) u16 Ktls[32 * 88];    // [d][kv]
    __shared__ __align__(16) u16 Pkls[KT * 8];     // [kv][8]
    __shared__ __align__(16) unsigned PW[4][16 * 36]; // per-wave packed P: [q-row][kv/2 u32]

    int b = blockIdx.z, h = blockIdx.y;
    int t = threadIdx.x;
    int w = t >> 6, l = t & 63, lg = l >> 4, lr = l & 15;
    int q0 = blockIdx.x * 64 + w * 16;

    int qrow = q0 + lr;
    bool qtok = (qrow < NQc);
    int qrc = qrow < Nc ? qrow : Nc - 1;
    s8v qB = *(const s8v*)&q[((size_t)b * Nc + qrc) * Cc + h * Dc + lg * 8];

    s8v pqB = {0, 0, 0, 0, 0, 0, 0, 0};
    if (lg == 0 && qrow >= NQc && qrow < Nc)
        pqB = *(const s8v*)&p[((size_t)b * HWc + (qrow - NQc)) * 8];

    f32x4 accO[2] = {{0.f, 0.f, 0.f, 0.f}, {0.f, 0.f, 0.f, 0.f}};
    float mrun = -1e30f, lrun = 0.f;

    int srow = t >> 2, sseg = (t & 3) * 8;     // K staging
    int td = t >> 3, tks = (t & 7) * 8;        // Kt staging
    int prow = t >> 1, pseg = (t & 1) * 4;     // p staging
    const u16* ktbase = kt + ((size_t)(b * NHc + h) * Dc + td) * KTLDc;
    unsigned* PWr = &PW[w][lr * 36];
    int bsrc = lg * 20;  // broadcast source lane base (lr == lg*4+j lives there)

    // ---- prologue: load tile 0 into regs ----
    s8v kv8 = {0,0,0,0,0,0,0,0};
    if (srow < Nc)
        kv8 = *(const s8v*)&k[((size_t)b * Nc + srow) * Cc + h * Dc + sseg];
    s8v kt8 = *(const s8v*)&ktbase[tks];
    ushort4 p4 = make_ushort4(0, 0, 0, 0);
    if (t < 128 && prow >= NQc)
        p4 = *(const ushort4*)&p[((size_t)b * HWc + (prow - NQc)) * 8 + pseg];

    for (int ti = 0; ti < NT; ++ti) {
        int m0 = ti * KT;
        bool tail = (m0 + KT > Nc);
        __syncthreads();  // previous tile fully consumed
        *(s8v*)&Kls[srow * 40 + sseg] = kv8;
        *(s8v*)&Ktls[td * 88 + tks]   = kt8;
        if (t < 128) *(ushort4*)&Pkls[prow * 8 + pseg] = p4;
        __syncthreads();

        // ---- issue next tile's global loads (hide latency under compute) ----
        if (ti + 1 < NT) {
            int n0g = m0 + KT;
            kv8 = (s8v){0,0,0,0,0,0,0,0};
            int kvg = n0g + srow;
            if (kvg < Nc)
                kv8 = *(const s8v*)&k[((size_t)b * Nc + kvg) * Cc + h * Dc + sseg];
            kt8 = *(const s8v*)&ktbase[n0g + tks];
            p4 = make_ushort4(0, 0, 0, 0);
            if (t < 128) {
                int pg = n0g + prow;
                if (pg >= NQc && pg < Nc)
                    p4 = *(const ushort4*)&p[((size_t)b * HWc + (pg - NQc)) * 8 + pseg];
            }
        }

        // ---- S^T tiles: mfma(K, Q); mask via mfma(pk, pq) ----
        float sc[4][4];
#pragma unroll
        for (int cb = 0; cb < 4; ++cb) {
            s8v kA = *(s8v*)&Kls[(cb * 16 + lr) * 40 + lg * 8];
            f32x4 St = __builtin_amdgcn_mfma_f32_16x16x32_bf16(kA, qB, (f32x4){0.f,0.f,0.f,0.f}, 0, 0, 0);
            s8v pkA = {0, 0, 0, 0, 0, 0, 0, 0};
            if (lg == 0) pkA = *(s8v*)&Pkls[(cb * 16 + lr) * 8];
            f32x4 Mv = __builtin_amdgcn_mfma_f32_16x16x32_bf16(pkA, pqB, (f32x4){0.f,0.f,0.f,0.f}, 0, 0, 0);
            bool ktok = (ti == 0 && cb == 0 && lg < 2);  // kv-row < 8
#pragma unroll
            for (int j = 0; j < 4; ++j) {
                float mval = (qtok || ktok) ? 1.f : Mv[j];
                sc[cb][j] = St[j] * mval;
            }
        }
        // ---- online softmax, per-lane q-row ----
        float tmax = sc[0][0];
#pragma unroll
        for (int cb = 0; cb < 4; ++cb)
#pragma unroll
            for (int j = 0; j < 4; ++j) tmax = fmaxf(tmax, sc[cb][j]);
        tmax = fmaxf(tmax, __shfl_xor(tmax, 16));
        tmax = fmaxf(tmax, __shfl_xor(tmax, 32));
        float mnew = fmaxf(mrun, tmax);
        float scl = __expf(mrun - mnew);
        mrun = mnew;
        lrun *= scl;
        float sb0 = __shfl(scl, bsrc + 0);
        float sb1 = __shfl(scl, bsrc + 1);
        float sb2 = __shfl(scl, bsrc + 2);
        float sb3 = __shfl(scl, bsrc + 3);
        accO[0][0] *= sb0; accO[1][0] *= sb0;
        accO[0][1] *= sb1; accO[1][1] *= sb1;
        accO[0][2] *= sb2; accO[1][2] *= sb2;
        accO[0][3] *= sb3; accO[1][3] *= sb3;
        float tsum = 0.f;
#pragma unroll
        for (int cb = 0; cb < 4; ++cb)
#pragma unroll
            for (int j = 0; j < 4; ++j) {
                float ev = __expf(sc[cb][j] - mnew);
                if (tail && (cb != 0 || lg >= 2)) ev = 0.f;  // kv >= Nc
                sc[cb][j] = ev;
                tsum += ev;
            }
        tsum += __shfl_xor(tsum, 16);
        tsum += __shfl_xor(tsum, 32);
        lrun += tsum;
        // ---- pack P (bf16 pairs) into per-wave LDS (conflict-free, no swizzle) ----
#pragma unroll
        for (int cb = 0; cb < 4; ++cb) {
            uint2 pk2;
            pk2.x = cvtpk2(sc[cb][0], sc[cb][1]);
            pk2.y = cvtpk2(sc[cb][2], sc[cb][3]);
            *(uint2*)&PWr[8 * cb + 2 * lg] = pk2;
        }
        // ---- PV: O += P @ V (V == scaled K via transposed tile); per-wave, no barrier ----
#pragma unroll
        for (int kc = 0; kc < 2; ++kc) {
            s8v pA = *(s8v*)&PWr[16 * kc + 4 * lg];
#pragma unroll
            for (int db = 0; db < 2; ++db) {
                s8v vB = *(s8v*)&Ktls[(db * 16 + lr) * 88 + kc * 32 + lg * 8];
                accO[db] = __builtin_amdgcn_mfma_f32_16x16x32_bf16(pA, vB, accO[db], 0, 0, 0);
            }
        }
    }

    float lb[4];
#pragma unroll
    for (int j = 0; j < 4; ++j) lb[j] = __shfl(lrun, bsrc + j);
#pragma unroll
    for (int db = 0; db < 2; ++db)
#pragma unroll
        for (int j = 0; j < 4; ++j) {
            int rowg = q0 + lg * 4 + j;
            if (rowg < Nc)
                o[((size_t)b * Nc + rowg) * Cc + h * Dc + db * 16 + lr] = f2bf(accO[db][j] / lb[j]);
        }
}

extern "C" void kernel_launch(void* const* d_in, const int* in_sizes, int n_in,
                              void* d_out, int out_size, void* d_ws, size_t ws_size,
                              hipStream_t stream)
{
    const float* x       = (const float*)d_in[0];
    const float* queries = (const float*)d_in[1];
    const int*   epoch   = (const int*)d_in[2];
    const float* pos_w   = (const float*)d_in[3];
    const float* pos_b   = (const float*)d_in[4];
    const float* ln1_g   = (const float*)d_in[5];
    const float* ln1_b   = (const float*)d_in[6];
    const float* q_w     = (const float*)d_in[7];
    const float* q_b     = (const float*)d_in[8];
    const float* k_w     = (const float*)d_in[9];
    const float* k_b     = (const float*)d_in[10];
    const float* v_w     = (const float*)d_in[11];
    const float* v_b     = (const float*)d_in[12];
    const float* lepe_w  = (const float*)d_in[13];
    const float* lepe_b  = (const float*)d_in[14];
    const float* out_w   = (const float*)d_in[15];
    const float* out_b   = (const float*)d_in[16];
    const float* ln2_g   = (const float*)d_in[17];
    const float* ln2_b   = (const float*)d_in[18];
    const float* fc1_w   = (const float*)d_in[19];
    const float* fc1_b   = (const float*)d_in[20];
    const float* fc2_w   = (const float*)d_in[21];
    const float* fc2_b   = (const float*)d_in[22];

    float* ws = (float*)d_ws;
    float* xq  = ws;                        // f32, 2,367,488
    float* vb  = ws + 2367488;              // f32, 2,367,488
    u16*  ybf  = (u16*)(ws + 4734976);      // bf16 2,367,488
    u16*  qbf  = (u16*)(ws + 5918720);      // bf16 2,367,488
    u16*  kbf  = (u16*)(ws + 7102464);      // bf16 2,367,488
    u16*  ktbf = (u16*)(ws + 8286208);      // bf16 4*8*32*2368 = 2,424,832
    u16*  pbf  = (u16*)(ws + 9498624);      // bf16 73,728
    u16*  obf  = (u16*)(ws + 9535488);      // bf16 2,367,488
    u16*  wbf  = (u16*)(ws + 10719232);     // bf16 786,432 (weights)
    u16*  ffn  = qbf;                       // bf16 9,469,952 (aliases qbf..obf, dead by then)

    u16* w_q  = wbf;
    u16* w_k  = wbf + 65536;
    u16* w_v  = wbf + 131072;
    u16* w_o  = wbf + 196608;
    u16* w_f1 = wbf + 262144;
    u16* w_f2 = wbf + 524288;

    const float kscale = 0.17677669529663687f; // (256/8)^-0.5

    convert_weights_kernel<<<768, 256, 0, stream>>>(q_w, k_w, v_w, out_w, fc1_w, fc2_w, wbf);
    zero_ktpad_kernel<<<224, 256, 0, stream>>>(ktbf);
    pos_conv_kernel<<<9216, 256, 0, stream>>>(x, pos_w, pos_b, xq);
    fill_queries_kernel<<<32, 256, 0, stream>>>(queries, xq);
    region_p_kernel<<<2304, 256, 0, stream>>>(xq, queries, epoch, pbf);
    ln_kernel<<<2312, 256, 0, stream>>>(xq, ln1_g, ln1_b, ybf, MRc);

    dim3 g256(4, 145);
    mfma_gemm_kernel<0,0,1><<<g256, 256, 0, stream>>>(ybf, w_q, q_b, nullptr, nullptr, qbf, nullptr, MRc, 256, 256, 1.0f);
    mfma_gemm_kernel<0,0,2><<<g256, 256, 0, stream>>>(ybf, w_k, k_b, nullptr, nullptr, kbf, ktbf, MRc, 256, 256, kscale);
    mfma_gemm_kernel<0,0,0><<<g256, 256, 0, stream>>>(ybf, w_v, v_b, nullptr, vb, nullptr, nullptr, MRc, 256, 256, 1.0f);

    attn_mfma_kernel<<<dim3(37, 8, 4), 256, 0, stream>>>(qbf, kbf, ktbf, pbf, obf);
    lepe_conv_add_kernel<<<9216, 256, 0, stream>>>(vb, lepe_w, lepe_b, obf);

    mfma_gemm_kernel<0,1,0><<<g256, 256, 0, stream>>>(obf, w_o, out_b, xq, xq, nullptr, nullptr, MRc, 256, 256, 1.0f);

    ln_kernel<<<2312, 256, 0, stream>>>(xq, ln2_g, ln2_b, ybf, MRc);
    mfma_gemm_kernel<1,0,1><<<dim3(16, 145), 256, 0, stream>>>(ybf, w_f1, fc1_b, nullptr, nullptr, ffn, nullptr, MRc, 1024, 256, 1.0f);
    mfma_gemm_kernel<0,1,3><<<g256, 256, 0, stream>>>(ffn, w_f2, fc2_b, xq, (float*)d_out, nullptr, nullptr, MRc, 256, 1024, 1.0f);
}